// Round 6
// baseline (285.161 us; speedup 1.0000x reference)
//
#include <hip/hip_runtime.h>
#include <hip/hip_bf16.h>

// ---- problem constants ----
#define Bb    2
#define Cc    128
#define HWp   16384    // 128*128 (one channel plane)
#define NBLK  64
#define BNOD  16
#define NPix  256
#define Nn    1024

// ---- ws layout (float element offsets) ----
#define OQ    0u        // Q      [B][NBLK][BNOD][NP]   524288
#define OF    524288u   // feats  [B][N][C]             262144
#define OADJ  786432u   // adj    [B][N][N]            2097152
#define OFR   2883584u  // Fr     [S][B][N][C]          786432
#define OFN   3670016u  // Fn     [S][B][N][C]          786432
#define OGI   4456448u  // gi     [S][B][N]               6144
#define OGJ   4462592u  // gj     [S][B][N]               6144
#define OOUT  4468736u  // out / agg-partial0 [S][B][N][C] 786432
#define OBNS  5255168u  // bn sum [S][C]                   384
#define OBNQ  5255552u  // bn sq  [S][C]                   384
#define OPOOL 5255936u  // pool   [S][B][C]                768
#define OP2   5256704u  // pool2  [S][B][C]                768
#define OCOEF 5257472u  // coefc  [S][B][C]                768
#define OYS   5258240u  // ys     [S][B][N][C]          786432
#define OYF   6044672u  // yfin   [B][N][C]             262144
// OFT (featsT [B][C][N]) overlays OYS: live only proj2->adj.
// OPART (agg partial1 [S][B][N][C]) also overlays OYS: live only agg->bnstat.
// OYS proper is first written by k_bn_att (after bnstat). Ordering is stream-serial.
#define OFT   OYS
#define OPART OYS

// ---------------- P1: logits + softmax over 16 nodes -> Q (+ zero-init) ----------------
__global__ __launch_bounds__(256) void k_proj1(const float* __restrict__ x,
                                               const float* __restrict__ anchor,
                                               const float* __restrict__ sigma_raw,
                                               float* __restrict__ ws) {
    const int blk = blockIdx.x, b = blockIdx.y;
    const int t = threadIdx.x;                 // pixel p
    if (blk == 0 && b == 0) {
        for (int i = t; i < 1536; i += 256) ws[OBNS + i] = 0.0f;  // BNS+BNQ+POOL
    }
    __shared__ float2 pairs[128][16];          // [c][k] = {isig, anc*isig}, 16KB
    for (int e = t; e < 16 * 128; e += 256) {
        int k = e >> 7, c = e & 127;
        int n = blk * 16 + k;
        float a    = anchor[n * 128 + c];
        float sr   = sigma_raw[n * 128 + c];
        float isig = 1.0f + __expf(-sr);       // 1/sigmoid(sr)
        pairs[c][k] = make_float2(isig, a * isig);
    }
    __syncthreads();
    const int h = (blk >> 3) * 16 + (t >> 4);
    const int w = (blk & 7) * 16 + (t & 15);
    const float* xp = x + (size_t)b * Cc * HWp + (size_t)h * 128 + w;
    float acc[16];
#pragma unroll
    for (int k = 0; k < 16; k++) acc[k] = 0.0f;
    for (int c = 0; c < 128; c++) {
        float pv = xp[(size_t)c * HWp];
#pragma unroll
        for (int k = 0; k < 16; k++) {
            float2 pr = pairs[c][k];
            float d = fmaf(pv, pr.x, -pr.y);   // (pix-anc)/sig
            acc[k] = fmaf(d, d, acc[k]);
        }
    }
    float m = acc[0];
#pragma unroll
    for (int k = 1; k < 16; k++) m = fminf(m, acc[k]);
    float ssum = 0.0f, ev[16];
#pragma unroll
    for (int k = 0; k < 16; k++) { ev[k] = __expf(0.5f * (m - acc[k])); ssum += ev[k]; }
    float inv = 1.0f / ssum;
    float* Qp = ws + OQ + ((size_t)(b * 64 + blk) * 16) * 256 + t;
#pragma unroll
    for (int k = 0; k < 16; k++) Qp[k * 256] = ev[k] * inv;
}

// ---------------- P2: nodes -> per-node L2 normalized feats (row-major + transposed) ----------------
__global__ __launch_bounds__(256) void k_proj2(const float* __restrict__ x,
                                               const float* __restrict__ anchor,
                                               const float* __restrict__ sigma_raw,
                                               float* __restrict__ ws) {
    const int blk = blockIdx.x, b = blockIdx.y;
    const int t = threadIdx.x;
    __shared__ float Ql[16][256];      // 16 KB
    __shared__ float pixl[32][258];    // 33 KB (padded)
    __shared__ float vbuf[16][132];    // 8.4 KB
    __shared__ float invn[16];
    const float* Qg = ws + OQ + (size_t)(b * 64 + blk) * 16 * 256;
    for (int e = t; e < 16 * 256; e += 256) Ql[e >> 8][e & 255] = Qg[e];
    const int cq = t & 31;
    const int k0 = (t >> 5) * 2;
    const int n0 = blk * 16 + k0;
    const int h0 = (blk >> 3) * 16, w0 = (blk & 7) * 16;
    __syncthreads();
    float S0a = 0.0f, S0b = 0.0f;
    for (int p = 0; p < 256; p++) { S0a += Ql[k0][p]; S0b += Ql[k0 + 1][p]; }
    const float i0a = 1.0f / (S0a + 1e-9f);
    const float i0b = 1.0f / (S0b + 1e-9f);
    float nsqa = 0.0f, nsqb = 0.0f;
    for (int q = 0; q < 4; q++) {
        const int c = q * 32 + cq;
        __syncthreads();
        for (int e = t; e < 32 * 256; e += 256) {
            int cc = e >> 8, p = e & 255;
            pixl[cc][p] = x[((size_t)b * Cc + (q * 32 + cc)) * HWp
                            + (size_t)(h0 + (p >> 4)) * 128 + (w0 + (p & 15))];
        }
        __syncthreads();
        float s1a = 0.0f, s1b = 0.0f;
        for (int p = 0; p < 256; p++) {
            float pv = pixl[cq][p];
            s1a = fmaf(Ql[k0][p], pv, s1a);
            s1b = fmaf(Ql[k0 + 1][p], pv, s1b);
        }
        float isa = 1.0f + __expf(-sigma_raw[(n0)     * 128 + c]);
        float isb = 1.0f + __expf(-sigma_raw[(n0 + 1) * 128 + c]);
        float aa  = anchor[(n0)     * 128 + c];
        float ab  = anchor[(n0 + 1) * 128 + c];
        float va = isa * (s1a - aa * S0a) * i0a;
        float vb = isb * (s1b - ab * S0b) * i0b;
        vbuf[k0][c]     = va;
        vbuf[k0 + 1][c] = vb;
        nsqa = fmaf(va, va, nsqa);
        nsqb = fmaf(vb, vb, nsqb);
    }
#pragma unroll
    for (int off = 16; off >= 1; off >>= 1) {
        nsqa += __shfl_xor(nsqa, off, 64);
        nsqb += __shfl_xor(nsqb, off, 64);
    }
    if (cq == 0) {
        invn[k0]     = 1.0f / fmaxf(sqrtf(nsqa), 1e-12f);
        invn[k0 + 1] = 1.0f / fmaxf(sqrtf(nsqb), 1e-12f);
    }
    __syncthreads();
    for (int e = t; e < 16 * 128; e += 256) {
        int k = e >> 7, c = e & 127;
        ws[OF + ((size_t)b * Nn + blk * 16 + k) * 128 + c] = vbuf[k][c] * invn[k];
    }
#pragma unroll
    for (int pass = 0; pass < 8; pass++) {
        int k = t & 15, c = (t >> 4) + pass * 16;
        ws[OFT + ((size_t)b * 128 + c) * 1024 + blk * 16 + k] = vbuf[k][c] * invn[k];
    }
}

// ---------------- feats @ W_root / W_nbr, gate dots ----------------
__global__ __launch_bounds__(256) void k_feat_mm(const float* __restrict__ W_root,
                                                 const float* __restrict__ W_nbr,
                                                 const float* __restrict__ wgs,
                                                 const float* __restrict__ wgd,
                                                 float* __restrict__ ws) {
    const int tile = blockIdx.x, b = blockIdx.y, s = blockIdx.z;
    const int t = threadIdx.x;
    __shared__ float fl[16][132];
    const float* F = ws + OF + ((size_t)b * Nn + tile * 16) * 128;
    for (int e = t; e < 16 * 128; e += 256) fl[e >> 7][e & 127] = F[e];
    __syncthreads();
    const int cout = t & 127, ih = t >> 7;
    float ar[8], an[8];
#pragma unroll
    for (int q = 0; q < 8; q++) { ar[q] = 0.0f; an[q] = 0.0f; }
    const float* Wr = W_root + s * 16384;
    const float* Wn = W_nbr + s * 16384;
    for (int cin = 0; cin < 128; cin++) {
        float wr = Wr[cin * 128 + cout];
        float wn = Wn[cin * 128 + cout];
#pragma unroll
        for (int q = 0; q < 8; q++) {
            float f = fl[ih * 8 + q][cin];
            ar[q] = fmaf(f, wr, ar[q]);
            an[q] = fmaf(f, wn, an[q]);
        }
    }
    const int sb = s * 2 + b;
#pragma unroll
    for (int q = 0; q < 8; q++) {
        int row = tile * 16 + ih * 8 + q;
        ws[OFR + ((size_t)sb * Nn + row) * 128 + cout] = ar[q];
        ws[OFN + ((size_t)sb * Nn + row) * 128 + cout] = an[q];
    }
    if (t < 16) {
        int row = tile * 16 + t;
        float g1 = 0.0f, g2 = 0.0f;
        for (int c = 0; c < 128; c++) {
            float f = fl[t][c];
            g1 = fmaf(f, wgs[s * 128 + c], g1);
            g2 = fmaf(f, wgd[s * 128 + c], g2);
        }
        ws[OGI + (size_t)sb * Nn + row] = g1;
        ws[OGJ + (size_t)sb * Nn + row] = g2;
    }
}

// ---------------- adj = feats @ feats^T (64x64 tiles, 4x4 reg tiles, featsT layout) ----------------
__global__ __launch_bounds__(256) void k_adj(float* __restrict__ ws) {
    const int jt = blockIdx.x, it = blockIdx.y, b = blockIdx.z;
    const int t = threadIdx.x;
    __shared__ float FiT[64][68];   // [c][i]
    __shared__ float FjT[64][68];   // [c][j]
    const float* FT = ws + OFT + (size_t)b * 128 * 1024;
    const int tx = t & 15, ty = t >> 4;
    float acc[4][4];
#pragma unroll
    for (int r = 0; r < 4; r++)
#pragma unroll
        for (int e = 0; e < 4; e++) acc[r][e] = 0.0f;
    for (int ch = 0; ch < 2; ch++) {
        __syncthreads();
#pragma unroll
        for (int k = 0; k < 4; k++) {
            int idx = k * 256 + t;
            int cc = idx >> 4, n4 = (idx & 15) * 4;
            *(float4*)&FiT[cc][n4] =
                *(const float4*)(FT + (size_t)(ch * 64 + cc) * 1024 + it * 64 + n4);
            *(float4*)&FjT[cc][n4] =
                *(const float4*)(FT + (size_t)(ch * 64 + cc) * 1024 + jt * 64 + n4);
        }
        __syncthreads();
        for (int c = 0; c < 64; c++) {
            float4 fi = *(const float4*)&FiT[c][ty * 4];
            float4 fj = *(const float4*)&FjT[c][tx * 4];
            const float fiv[4] = {fi.x, fi.y, fi.z, fi.w};
            const float fjv[4] = {fj.x, fj.y, fj.z, fj.w};
#pragma unroll
            for (int r = 0; r < 4; r++)
#pragma unroll
                for (int e = 0; e < 4; e++)
                    acc[r][e] = fmaf(fiv[r], fjv[e], acc[r][e]);
        }
    }
    float* A = ws + OADJ + (size_t)b * Nn * Nn;
#pragma unroll
    for (int r = 0; r < 4; r++) {
        *(float4*)&A[(size_t)(it * 64 + ty * 4 + r) * Nn + jt * 64 + tx * 4] =
            make_float4(acc[r][0], acc[r][1], acc[r][2], acc[r][3]);
    }
}

// ---------------- masked/gated aggregation, j-split into 2 partial buffers ----------------
// grid (64 tiles, jhalf*4 + b*2 + ch, 3 s); 256 threads.
__global__ __launch_bounds__(256) void k_agg(const float* __restrict__ b_gate,
                                             float* __restrict__ ws) {
    const int tile = blockIdx.x;
    const int yy = blockIdx.y;                 // jhalf*4 + b*2 + ch
    const int jhalf = yy >> 2;
    const int b = (yy >> 1) & 1, ch = yy & 1;
    const int s = blockIdx.z;
    const int sb = s * 2 + b;
    const int ch0 = ch * 64;
    const int t = threadIdx.x;

    __shared__ float sm[8704];                 // 34.8 KB, overlaid
    float* FnL  = sm;                          // [64][68]  (staging phase)
    float* wglT = sm + 4352;                   // [64][20]
    float* gil  = sm + 5632;                   // [16]
    float* accT = sm;                          // [8][16][64] (epilogue phase)

    const float* adj = ws + OADJ + (size_t)b * Nn * Nn;
    const float* gjp = ws + OGJ + (size_t)sb * Nn;
    const float* Fn  = ws + OFN + (size_t)sb * Nn * 128;
    const float bg = b_gate[s];
    if (t < 16) gil[t] = ws[OGI + (size_t)sb * Nn + tile * 16 + t];

    const int cg   = t & 15;                   // channel group (4 ch)
    const int rowg = (t >> 4) & 1;             // 8-row group
    const int jg   = t >> 5;                   // j slice 0..7

    float acc[8][4];
#pragma unroll
    for (int r = 0; r < 8; r++)
#pragma unroll
        for (int m = 0; m < 4; m++) acc[r][m] = 0.0f;

    for (int jt = jhalf * 8; jt < jhalf * 8 + 8; jt++) {
        __syncthreads();                       // previous tile's readers done (also covers gil)
        // stage Fn tile: 64 j x 64 ch (this half)
#pragma unroll
        for (int k = 0; k < 4; k++) {
            int idx = t + k * 256;
            int jj = idx >> 4, cc4 = (idx & 15) * 4;
            float4 v = *(const float4*)(Fn + (size_t)(jt * 64 + jj) * 128 + ch0 + cc4);
            *(float4*)&FnL[jj * 68 + cc4] = v;
        }
        // build wglT tile: 64 j x 16 rows
        {
            int jj = t >> 2, il4 = (t & 3) * 4;
            int j = jt * 64 + jj;
            float gjv = gjp[j];
            float4 wv;
            float* wp = (float*)&wv;
#pragma unroll
            for (int r = 0; r < 4; r++) {
                int il = il4 + r;
                int i = tile * 16 + il;
                float a = adj[(size_t)i * Nn + j];
                bool pass;
                if (s == 0)      pass = (a > 0.7f) && ((i >> 4) == (j >> 4));
                else if (s == 1) pass = (a > 0.5f) && ((i >> 4) != (j >> 4));
                else             pass = (a > 0.3f);
                float g = 1.0f / (1.0f + __expf(-(gil[il] + gjv + bg)));
                wp[r] = pass ? a * g : 0.0f;
            }
            *(float4*)&wglT[jj * 20 + il4] = wv;
        }
        __syncthreads();
#pragma unroll
        for (int u = 0; u < 8; u++) {
            const int jl = jg * 8 + u;
            const float4 fn = *(const float4*)&FnL[jl * 68 + cg * 4];
            const float4 wa = *(const float4*)&wglT[jl * 20 + rowg * 8];
            const float4 wb = *(const float4*)&wglT[jl * 20 + rowg * 8 + 4];
            const float f[4] = {fn.x, fn.y, fn.z, fn.w};
            const float w[8] = {wa.x, wa.y, wa.z, wa.w, wb.x, wb.y, wb.z, wb.w};
#pragma unroll
            for (int r = 0; r < 8; r++)
#pragma unroll
                for (int m = 0; m < 4; m++)
                    acc[r][m] = fmaf(w[r], f[m], acc[r][m]);
        }
    }
    __syncthreads();
#pragma unroll
    for (int r = 0; r < 8; r++) {
        int row = rowg * 8 + r;
        *(float4*)&accT[(jg * 16 + row) * 64 + cg * 4] =
            make_float4(acc[r][0], acc[r][1], acc[r][2], acc[r][3]);
    }
    __syncthreads();
    // reduce 8 slices, store to partial buffer (no atomics)
    {
        const int c = t & 63, rowq = t >> 6;
        float* part = ws + (jhalf ? OPART : OOUT) + ((size_t)sb * Nn + tile * 16) * 128;
#pragma unroll
        for (int rr = 0; rr < 4; rr++) {
            int row = rowq * 4 + rr;
            float v = 0.0f;
#pragma unroll
            for (int g = 0; g < 8; g++) v += accT[(g * 16 + row) * 64 + c];
            part[row * 128 + ch0 + c] = v;
        }
    }
}

// ---------------- sum partials + Fr -> OOUT, BN statistics ----------------
__global__ __launch_bounds__(256) void k_bnstat(float* __restrict__ ws) {
    const int tile = blockIdx.x, b = blockIdx.y, s = blockIdx.z;
    const int sb = s * 2 + b;
    const int t = threadIdx.x;
    __shared__ float bnr[4][128];
    const int c = t & 127, ih = t >> 7;
    const size_t base = ((size_t)sb * Nn + tile * 16) * 128;
    const float* p1 = ws + OPART + base;
    const float* Fr = ws + OFR + base;
    float* outp = ws + OOUT + base;
    float s1 = 0.0f, s2 = 0.0f;
#pragma unroll
    for (int q = 0; q < 8; q++) {
        int idx = (ih * 8 + q) * 128 + c;
        float v = outp[idx] + p1[idx] + Fr[idx];
        outp[idx] = v;
        s1 += v;
        s2 = fmaf(v, v, s2);
    }
    bnr[ih][c] = s1;
    bnr[2 + ih][c] = s2;
    __syncthreads();
    if (t < 128) {
        atomicAdd(&ws[OBNS + s * 128 + t], bnr[0][t] + bnr[1][t]);
        atomicAdd(&ws[OBNQ + s * 128 + t], bnr[2][t] + bnr[3][t]);
    }
}

// ---------------- BN + residual + NodeAtt + relu + max-pool ----------------
__global__ __launch_bounds__(256) void k_bn_att(const float* __restrict__ bn_gamma,
                                                const float* __restrict__ bn_beta,
                                                const float* __restrict__ att_W,
                                                const float* __restrict__ att_b,
                                                float* __restrict__ ws) {
    const int tile = blockIdx.x, b = blockIdx.y, s = blockIdx.z;
    const int t = threadIdx.x;
    __shared__ float hl[16][132];
    const int sb = s * 2 + b;
    const int cthr = t & 127, ih = t >> 7;
    float mu = ws[OBNS + s * 128 + cthr] * (1.0f / 2048.0f);
    float ms = ws[OBNQ + s * 128 + cthr] * (1.0f / 2048.0f);
    float var = ms - mu * mu;
    float gam = bn_gamma[s * 128 + cthr];
    float bet = bn_beta[s * 128 + cthr];
    float scal = gam * rsqrtf(var + 1e-5f);
    const float* outp = ws + OOUT + ((size_t)sb * Nn + tile * 16) * 128;
    const float* F = ws + OF + ((size_t)b * Nn + tile * 16) * 128;
#pragma unroll
    for (int q = 0; q < 8; q++) {
        int il = ih * 8 + q;
        float v = outp[(size_t)il * 128 + cthr];
        hl[il][cthr] = scal * (v - mu) + bet + F[(size_t)il * 128 + cthr];
    }
    __syncthreads();
    float acc[8] = {0,0,0,0,0,0,0,0};
    const float* AW = att_W + s * 16384;
    for (int cin = 0; cin < 128; cin++) {
        float w = AW[cin * 128 + cthr];
#pragma unroll
        for (int q = 0; q < 8; q++) acc[q] = fmaf(hl[ih * 8 + q][cin], w, acc[q]);
    }
    float ab = att_b[s * 128 + cthr];
    float* ys = ws + OYS + ((size_t)sb * Nn + tile * 16) * 128;
    float mx = 0.0f;
#pragma unroll
    for (int q = 0; q < 8; q++) {
        int il = ih * 8 + q;
        float h = hl[il][cthr];
        float sg = 1.0f / (1.0f + __expf(-(acc[q] + ab)));
        float y = fmaxf(sg * h, 0.0f);
        ys[(size_t)il * 128 + cthr] = y;
        mx = fmaxf(mx, y);
    }
    atomicMax((unsigned int*)(ws + OPOOL + sb * 128 + cthr), __float_as_uint(mx));
}

// ---------------- pooled MLP ----------------
__global__ __launch_bounds__(128) void k_mlp(const float* __restrict__ W1, const float* __restrict__ b1,
                                             const float* __restrict__ W2, const float* __restrict__ b2,
                                             float* __restrict__ ws) {
    const int sb = blockIdx.x;      // s*2+b
    const int s = sb >> 1;
    const int t = threadIdx.x;      // cout
    __shared__ float pl[128], z1[128];
    pl[t] = ws[OPOOL + sb * 128 + t];
    __syncthreads();
    float a = b1[s * 128 + t];
    for (int cin = 0; cin < 128; cin++)
        a = fmaf(pl[cin], W1[s * 16384 + cin * 128 + t], a);
    z1[t] = fmaxf(a, 0.0f);
    __syncthreads();
    float a2 = b2[s * 128 + t];
    for (int cin = 0; cin < 128; cin++)
        a2 = fmaf(z1[cin], W2[s * 16384 + cin * 128 + t], a2);
    ws[OP2 + sb * 128 + t] = 1.0f / (1.0f + __expf(-a2));
}

// ---------------- scale attention coefficients ----------------
__global__ __launch_bounds__(256) void k_coef(const float* __restrict__ lineA_w,
                                              const float* __restrict__ lineA_b,
                                              float* __restrict__ ws) {
    __shared__ float av[2][3];
    const int t = threadIdx.x;
    if (t < 6) {
        int s = t >> 1, b = t & 1;
        float acc = lineA_b[s];
        for (int c = 0; c < 128; c++)
            acc = fmaf(ws[OP2 + (s * 2 + b) * 128 + c], lineA_w[s * 128 + c], acc);
        av[b][s] = acc;
    }
    __syncthreads();
    for (int e = t; e < 768; e += 256) {
        int s = e >> 8, b = (e >> 7) & 1;
        float m = fmaxf(av[b][0], fmaxf(av[b][1], av[b][2]));
        float e0 = __expf(av[b][0] - m), e1 = __expf(av[b][1] - m), e2 = __expf(av[b][2] - m);
        float A = (s == 0 ? e0 : (s == 1 ? e1 : e2)) / (e0 + e1 + e2);
        ws[OCOEF + e] = A * ws[OP2 + e];
    }
}

// ---------------- fused combination + lineFu matmul ----------------
__global__ __launch_bounds__(256) void k_fuse(const float* __restrict__ lineFu_W,
                                              const float* __restrict__ lineFu_b,
                                              float* __restrict__ ws) {
    const int tile = blockIdx.x, b = blockIdx.y;
    const int t = threadIdx.x;
    __shared__ float fl[16][132];
    const int cthr = t & 127, ih = t >> 7;
    float c0 = ws[OCOEF + (0 * 2 + b) * 128 + cthr];
    float c1 = ws[OCOEF + (1 * 2 + b) * 128 + cthr];
    float c2 = ws[OCOEF + (2 * 2 + b) * 128 + cthr];
#pragma unroll
    for (int q = 0; q < 8; q++) {
        int il = ih * 8 + q;
        size_t row = (size_t)(tile * 16 + il) * 128 + cthr;
        float v = c0 * ws[OYS + (size_t)(0 * 2 + b) * Nn * 128 + row]
                + c1 * ws[OYS + (size_t)(1 * 2 + b) * Nn * 128 + row]
                + c2 * ws[OYS + (size_t)(2 * 2 + b) * Nn * 128 + row];
        fl[il][cthr] = v;
    }
    __syncthreads();
    float acc[8] = {0,0,0,0,0,0,0,0};
    for (int cin = 0; cin < 128; cin++) {
        float w = lineFu_W[cin * 128 + cthr];
#pragma unroll
        for (int q = 0; q < 8; q++) acc[q] = fmaf(fl[ih * 8 + q][cin], w, acc[q]);
    }
    float bb = lineFu_b[cthr];
#pragma unroll
    for (int q = 0; q < 8; q++) {
        int row = tile * 16 + ih * 8 + q;
        ws[OYF + ((size_t)b * Nn + row) * 128 + cthr] = acc[q] + bb;
    }
}

// ---------------- reprojection + residual ----------------
__global__ __launch_bounds__(256) void k_reproj(const float* __restrict__ x,
                                                const float* __restrict__ ws,
                                                float* __restrict__ out) {
    const int blk = blockIdx.x, b = blockIdx.y;
    const int t = threadIdx.x;                 // pixel p
    __shared__ float yl[16][132];
    const float* YF = ws + OYF + ((size_t)b * Nn + blk * 16) * 128;
    for (int e = t; e < 16 * 128; e += 256) yl[e >> 7][e & 127] = YF[e];
    float qv[16];
    const float* Qg = ws + OQ + (size_t)(b * 64 + blk) * 16 * 256;
#pragma unroll
    for (int k = 0; k < 16; k++) qv[k] = Qg[k * 256 + t];
    __syncthreads();
    const int h = (blk >> 3) * 16 + (t >> 4);
    const int w = (blk & 7) * 16 + (t & 15);
    const float* xp = x + (size_t)b * Cc * HWp + (size_t)h * 128 + w;
    float* op = out + (size_t)b * Cc * HWp + (size_t)h * 128 + w;
    for (int c = 0; c < 128; c++) {
        float r = 0.0f;
#pragma unroll
        for (int k = 0; k < 16; k++) r = fmaf(qv[k], yl[k][c], r);
        op[(size_t)c * HWp] = r + xp[(size_t)c * HWp];
    }
}

extern "C" void kernel_launch(void* const* d_in, const int* in_sizes, int n_in,
                              void* d_out, int out_size, void* d_ws, size_t ws_size,
                              hipStream_t stream) {
    const float* x         = (const float*)d_in[0];
    const float* anchor    = (const float*)d_in[1];
    const float* sigma_raw = (const float*)d_in[2];
    const float* W_root    = (const float*)d_in[3];
    const float* W_nbr     = (const float*)d_in[4];
    const float* wgs       = (const float*)d_in[5];
    const float* wgd       = (const float*)d_in[6];
    const float* b_gate    = (const float*)d_in[7];
    const float* bn_gamma  = (const float*)d_in[8];
    const float* bn_beta   = (const float*)d_in[9];
    const float* att_W     = (const float*)d_in[10];
    const float* att_b     = (const float*)d_in[11];
    const float* mlp_W1    = (const float*)d_in[12];
    const float* mlp_b1    = (const float*)d_in[13];
    const float* mlp_W2    = (const float*)d_in[14];
    const float* mlp_b2    = (const float*)d_in[15];
    const float* lineA_w   = (const float*)d_in[16];
    const float* lineA_b   = (const float*)d_in[17];
    const float* lineFu_W  = (const float*)d_in[18];
    const float* lineFu_b  = (const float*)d_in[19];
    float* out = (float*)d_out;
    float* ws = (float*)d_ws;

    k_proj1  <<<dim3(64, 2),    dim3(256), 0, stream>>>(x, anchor, sigma_raw, ws);
    k_proj2  <<<dim3(64, 2),    dim3(256), 0, stream>>>(x, anchor, sigma_raw, ws);
    k_feat_mm<<<dim3(64, 2, 3), dim3(256), 0, stream>>>(W_root, W_nbr, wgs, wgd, ws);
    k_adj    <<<dim3(16, 16, 2),dim3(256), 0, stream>>>(ws);
    k_agg    <<<dim3(64, 8, 3), dim3(256), 0, stream>>>(b_gate, ws);
    k_bnstat <<<dim3(64, 2, 3), dim3(256), 0, stream>>>(ws);
    k_bn_att <<<dim3(64, 2, 3), dim3(256), 0, stream>>>(bn_gamma, bn_beta, att_W, att_b, ws);
    k_mlp    <<<dim3(6),        dim3(128), 0, stream>>>(mlp_W1, mlp_b1, mlp_W2, mlp_b2, ws);
    k_coef   <<<dim3(1),        dim3(256), 0, stream>>>(lineA_w, lineA_b, ws);
    k_fuse   <<<dim3(64, 2),    dim3(256), 0, stream>>>(lineFu_W, lineFu_b, ws);
    k_reproj <<<dim3(64, 2),    dim3(256), 0, stream>>>(x, ws, out);
}

// Round 7
// 244.064 us; speedup vs baseline: 1.1684x; 1.1684x over previous
//
#include <hip/hip_runtime.h>
#include <hip/hip_bf16.h>

// ---- problem constants ----
#define Bb    2
#define Cc    128
#define HWp   16384    // 128*128 (one channel plane)
#define NBLK  64
#define BNOD  16
#define NPix  256
#define Nn    1024

// ---- ws layout (float element offsets) ----
#define OQ    0u        // Q      [B][NBLK][BNOD][NP]   524288
#define OF    524288u   // feats  [B][N][C]             262144
#define OADJ  786432u   // adj    [B][N][N]            2097152
#define OFR   2883584u  // Fr     [S][B][N][C]          786432
#define OFN   3670016u  // FnT    bf16 [S*B][C][N]      (786432 bf16 = 393216 f-slots)
#define OGI   4456448u  // gi     [S][B][N]               6144
#define OGJ   4462592u  // gj     [S][B][N]               6144
#define OOUT  4468736u  // agg-acc / out [S][B][N][C]   786432
#define OBNS  5255168u  // bn sum [S][C]                   384
#define OBNQ  5255552u  // bn sq  [S][C]                   384
#define OPOOL 5255936u  // pool   [S][B][C]                768
#define OP2   5256704u  // pool2  [S][B][C]                768
#define OCOEF 5257472u  // coefc  [S][B][C]                768
#define OYS   5258240u  // ys     [S][B][N][C]          786432
#define OYF   6044672u  // yfin   [B][N][C]             262144
// OFT (featsT f32 [B][C][N]) overlays OYS: live only proj2->adj (OYS written later by k_bn_att).
#define OFT   OYS

typedef short s8v  __attribute__((ext_vector_type(8)));
typedef float f4v  __attribute__((ext_vector_type(4)));

__device__ __forceinline__ short f2bf(float f) {
    __hip_bfloat16 h = __float2bfloat16(f);
    return *reinterpret_cast<short*>(&h);
}

// ---------------- P1: logits + softmax over 16 nodes -> Q (pixel-split 4x, + zero-init) ----------------
__global__ __launch_bounds__(256) void k_proj1(const float* __restrict__ x,
                                               const float* __restrict__ anchor,
                                               const float* __restrict__ sigma_raw,
                                               float* __restrict__ ws) {
    const int blk = blockIdx.x, b = blockIdx.y, pg = blockIdx.z;
    const int t = threadIdx.x;
    if (blk == 0 && b == 0 && pg == 0) {
        for (int i = t; i < 1536; i += 256) ws[OBNS + i] = 0.0f;  // BNS+BNQ+POOL
    }
    __shared__ float2 pairs[128][16];          // 16 KB
    __shared__ float accp[4][64][17];          // 17.4 KB
    for (int e = t; e < 16 * 128; e += 256) {
        int k = e >> 7, c = e & 127;
        int n = blk * 16 + k;
        float a    = anchor[n * 128 + c];
        float sr   = sigma_raw[n * 128 + c];
        float isig = 1.0f + __expf(-sr);       // 1/sigmoid(sr)
        pairs[c][k] = make_float2(isig, a * isig);
    }
    __syncthreads();
    const int pl = t & 63, cq = t >> 6;
    const int p = pg * 64 + pl;
    const int h = (blk >> 3) * 16 + (p >> 4);
    const int w = (blk & 7) * 16 + (p & 15);
    const float* xp = x + (size_t)b * Cc * HWp + (size_t)h * 128 + w;
    float acc[16];
#pragma unroll
    for (int k = 0; k < 16; k++) acc[k] = 0.0f;
    for (int c = cq * 32; c < cq * 32 + 32; c++) {
        float pv = xp[(size_t)c * HWp];
#pragma unroll
        for (int k = 0; k < 16; k++) {
            float2 pr = pairs[c][k];
            float d = fmaf(pv, pr.x, -pr.y);
            acc[k] = fmaf(d, d, acc[k]);
        }
    }
#pragma unroll
    for (int k = 0; k < 16; k++) accp[cq][pl][k] = acc[k];
    __syncthreads();
    if (t < 64) {
        float a2[16];
#pragma unroll
        for (int k = 0; k < 16; k++)
            a2[k] = accp[0][t][k] + accp[1][t][k] + accp[2][t][k] + accp[3][t][k];
        float m = a2[0];
#pragma unroll
        for (int k = 1; k < 16; k++) m = fminf(m, a2[k]);
        float ssum = 0.0f, ev[16];
#pragma unroll
        for (int k = 0; k < 16; k++) { ev[k] = __expf(0.5f * (m - a2[k])); ssum += ev[k]; }
        float inv = 1.0f / ssum;
        float* Qp = ws + OQ + ((size_t)(b * 64 + blk) * 16) * 256 + p;
#pragma unroll
        for (int k = 0; k < 16; k++) Qp[k * 256] = ev[k] * inv;
    }
}

// ---------------- P2: nodes -> per-node L2 normalized feats (row-major + transposed) ----------------
__global__ __launch_bounds__(256) void k_proj2(const float* __restrict__ x,
                                               const float* __restrict__ anchor,
                                               const float* __restrict__ sigma_raw,
                                               float* __restrict__ ws) {
    const int blk = blockIdx.x, b = blockIdx.y;
    const int t = threadIdx.x;
    __shared__ float Ql[16][256];      // 16 KB
    __shared__ float pixl[32][258];    // 33 KB (padded)
    __shared__ float vbuf[16][132];    // 8.4 KB
    __shared__ float invn[16];
    const float* Qg = ws + OQ + (size_t)(b * 64 + blk) * 16 * 256;
    for (int e = t; e < 16 * 256; e += 256) Ql[e >> 8][e & 255] = Qg[e];
    const int cq = t & 31;
    const int k0 = (t >> 5) * 2;
    const int n0 = blk * 16 + k0;
    const int h0 = (blk >> 3) * 16, w0 = (blk & 7) * 16;
    __syncthreads();
    float S0a = 0.0f, S0b = 0.0f;
    for (int p = 0; p < 256; p++) { S0a += Ql[k0][p]; S0b += Ql[k0 + 1][p]; }
    const float i0a = 1.0f / (S0a + 1e-9f);
    const float i0b = 1.0f / (S0b + 1e-9f);
    float nsqa = 0.0f, nsqb = 0.0f;
    for (int q = 0; q < 4; q++) {
        const int c = q * 32 + cq;
        __syncthreads();
        for (int e = t; e < 32 * 256; e += 256) {
            int cc = e >> 8, p = e & 255;
            pixl[cc][p] = x[((size_t)b * Cc + (q * 32 + cc)) * HWp
                            + (size_t)(h0 + (p >> 4)) * 128 + (w0 + (p & 15))];
        }
        __syncthreads();
        float s1a = 0.0f, s1b = 0.0f;
        for (int p = 0; p < 256; p++) {
            float pv = pixl[cq][p];
            s1a = fmaf(Ql[k0][p], pv, s1a);
            s1b = fmaf(Ql[k0 + 1][p], pv, s1b);
        }
        float isa = 1.0f + __expf(-sigma_raw[(n0)     * 128 + c]);
        float isb = 1.0f + __expf(-sigma_raw[(n0 + 1) * 128 + c]);
        float aa  = anchor[(n0)     * 128 + c];
        float ab  = anchor[(n0 + 1) * 128 + c];
        float va = isa * (s1a - aa * S0a) * i0a;
        float vb = isb * (s1b - ab * S0b) * i0b;
        vbuf[k0][c]     = va;
        vbuf[k0 + 1][c] = vb;
        nsqa = fmaf(va, va, nsqa);
        nsqb = fmaf(vb, vb, nsqb);
    }
#pragma unroll
    for (int off = 16; off >= 1; off >>= 1) {
        nsqa += __shfl_xor(nsqa, off, 64);
        nsqb += __shfl_xor(nsqb, off, 64);
    }
    if (cq == 0) {
        invn[k0]     = 1.0f / fmaxf(sqrtf(nsqa), 1e-12f);
        invn[k0 + 1] = 1.0f / fmaxf(sqrtf(nsqb), 1e-12f);
    }
    __syncthreads();
    for (int e = t; e < 16 * 128; e += 256) {
        int k = e >> 7, c = e & 127;
        ws[OF + ((size_t)b * Nn + blk * 16 + k) * 128 + c] = vbuf[k][c] * invn[k];
    }
#pragma unroll
    for (int pass = 0; pass < 8; pass++) {
        int k = t & 15, c = (t >> 4) + pass * 16;
        ws[OFT + ((size_t)b * 128 + c) * 1024 + blk * 16 + k] = vbuf[k][c] * invn[k];
    }
}

// ---------------- feats @ W_root / W_nbr (FnT emitted as bf16), gate dots ----------------
__global__ __launch_bounds__(256) void k_feat_mm(const float* __restrict__ W_root,
                                                 const float* __restrict__ W_nbr,
                                                 const float* __restrict__ wgs,
                                                 const float* __restrict__ wgd,
                                                 float* __restrict__ ws) {
    const int tile = blockIdx.x, b = blockIdx.y, s = blockIdx.z;
    const int t = threadIdx.x;
    __shared__ float fl[16][132];
    const float* F = ws + OF + ((size_t)b * Nn + tile * 16) * 128;
    for (int e = t; e < 16 * 128; e += 256) fl[e >> 7][e & 127] = F[e];
    __syncthreads();
    const int cout = t & 127, ih = t >> 7;
    float ar[8], an[8];
#pragma unroll
    for (int q = 0; q < 8; q++) { ar[q] = 0.0f; an[q] = 0.0f; }
    const float* Wr = W_root + s * 16384;
    const float* Wn = W_nbr + s * 16384;
    for (int cin = 0; cin < 128; cin++) {
        float wr = Wr[cin * 128 + cout];
        float wn = Wn[cin * 128 + cout];
#pragma unroll
        for (int q = 0; q < 8; q++) {
            float f = fl[ih * 8 + q][cin];
            ar[q] = fmaf(f, wr, ar[q]);
            an[q] = fmaf(f, wn, an[q]);
        }
    }
    const int sb = s * 2 + b;
#pragma unroll
    for (int q = 0; q < 8; q++) {
        int row = tile * 16 + ih * 8 + q;
        ws[OFR + ((size_t)sb * Nn + row) * 128 + cout] = ar[q];
    }
    // FnT bf16 [sb][cout][node]: 8 consecutive nodes -> one 16B store
    {
        short hb[8];
#pragma unroll
        for (int q = 0; q < 8; q++) hb[q] = f2bf(an[q]);
        short* fnb = (short*)(ws + OFN);
        *(int4*)(fnb + (((size_t)sb * 128 + cout) << 10) + tile * 16 + ih * 8) = *(int4*)hb;
    }
    if (t < 16) {
        int row = tile * 16 + t;
        float g1 = 0.0f, g2 = 0.0f;
        for (int c = 0; c < 128; c++) {
            float f = fl[t][c];
            g1 = fmaf(f, wgs[s * 128 + c], g1);
            g2 = fmaf(f, wgd[s * 128 + c], g2);
        }
        ws[OGI + (size_t)sb * Nn + row] = g1;
        ws[OGJ + (size_t)sb * Nn + row] = g2;
    }
}

// ---------------- adj = feats @ feats^T (64x64 tiles) + zero OOUT for k_agg atomics ----------------
__global__ __launch_bounds__(256) void k_adj(float* __restrict__ ws) {
    const int jt = blockIdx.x, it = blockIdx.y, b = blockIdx.z;
    const int t = threadIdx.x;
    // zero the agg accumulator region (512 blocks x 1536 floats = 786432)
    {
        int bid = (b * 16 + it) * 16 + jt;
        for (int i = t; i < 1536; i += 256) ws[OOUT + (size_t)bid * 1536 + i] = 0.0f;
    }
    __shared__ float FiT[64][68];   // [c][i]
    __shared__ float FjT[64][68];   // [c][j]
    const float* FT = ws + OFT + (size_t)b * 128 * 1024;
    const int tx = t & 15, ty = t >> 4;
    float acc[4][4];
#pragma unroll
    for (int r = 0; r < 4; r++)
#pragma unroll
        for (int e = 0; e < 4; e++) acc[r][e] = 0.0f;
    for (int ch = 0; ch < 2; ch++) {
        __syncthreads();
#pragma unroll
        for (int k = 0; k < 4; k++) {
            int idx = k * 256 + t;
            int cc = idx >> 4, n4 = (idx & 15) * 4;
            *(float4*)&FiT[cc][n4] =
                *(const float4*)(FT + (size_t)(ch * 64 + cc) * 1024 + it * 64 + n4);
            *(float4*)&FjT[cc][n4] =
                *(const float4*)(FT + (size_t)(ch * 64 + cc) * 1024 + jt * 64 + n4);
        }
        __syncthreads();
        for (int c = 0; c < 64; c++) {
            float4 fi = *(const float4*)&FiT[c][ty * 4];
            float4 fj = *(const float4*)&FjT[c][tx * 4];
            const float fiv[4] = {fi.x, fi.y, fi.z, fi.w};
            const float fjv[4] = {fj.x, fj.y, fj.z, fj.w};
#pragma unroll
            for (int r = 0; r < 4; r++)
#pragma unroll
                for (int e = 0; e < 4; e++)
                    acc[r][e] = fmaf(fiv[r], fjv[e], acc[r][e]);
        }
    }
    float* A = ws + OADJ + (size_t)b * Nn * Nn;
#pragma unroll
    for (int r = 0; r < 4; r++) {
        *(float4*)&A[(size_t)(it * 64 + ty * 4 + r) * Nn + jt * 64 + tx * 4] =
            make_float4(acc[r][0], acc[r][1], acc[r][2], acc[r][3]);
    }
}

// ---------------- MFMA aggregation: agg[sb] = W(adj,gate,mask)[1024x1024] @ Fn[1024x128] ----------------
// grid (32 M-tiles, 2 K-halves, 6 sb); 256 threads (4 waves).
__global__ __launch_bounds__(256) void k_agg(const float* __restrict__ b_gate,
                                             float* __restrict__ ws) {
    const int mt = blockIdx.x, kh = blockIdx.y, sb = blockIdx.z;
    const int s = sb >> 1, b = sb & 1;
    const int t = threadIdx.x;
    const int i0 = mt * 32, j00 = kh * 512;
    __shared__ short A_s[32][136];   // 8.7 KB  bf16 W tile [i][k]
    __shared__ short B_s[128][136];  // 34.8 KB bf16 FnT tile [c][k]
    __shared__ float gil[32];
    if (t < 32) gil[t] = ws[OGI + (size_t)sb * Nn + i0 + t];
    const float bg = b_gate[s];
    const float* adj = ws + OADJ + (size_t)b * Nn * Nn;
    const float* gjp = ws + OGJ + (size_t)sb * Nn;
    const short* fnb = (const short*)(ws + OFN) + ((size_t)sb * 128 << 10);
    const int wid = t >> 6, lane = t & 63, quad = lane >> 4, l15 = lane & 15;
    f4v acc00 = {0,0,0,0}, acc01 = {0,0,0,0}, acc10 = {0,0,0,0}, acc11 = {0,0,0,0};

    for (int chunk = 0; chunk < 4; chunk++) {
        const int j0 = j00 + chunk * 128;
        __syncthreads();                       // prev chunk's readers done; gil visible
        // stage A: 32 i x 128 j, mask+gate -> bf16
        {
            const int i = t >> 3, jj = (t & 7) << 4;
            const float* ap = adj + (size_t)(i0 + i) * Nn + j0 + jj;
            float4 av0 = *(const float4*)(ap);
            float4 av1 = *(const float4*)(ap + 4);
            float4 av2 = *(const float4*)(ap + 8);
            float4 av3 = *(const float4*)(ap + 12);
            float4 gv0 = *(const float4*)(gjp + j0 + jj);
            float4 gv1 = *(const float4*)(gjp + j0 + jj + 4);
            float4 gv2 = *(const float4*)(gjp + j0 + jj + 8);
            float4 gv3 = *(const float4*)(gjp + j0 + jj + 12);
            float avf[16] = {av0.x,av0.y,av0.z,av0.w, av1.x,av1.y,av1.z,av1.w,
                             av2.x,av2.y,av2.z,av2.w, av3.x,av3.y,av3.z,av3.w};
            float gvf[16] = {gv0.x,gv0.y,gv0.z,gv0.w, gv1.x,gv1.y,gv1.z,gv1.w,
                             gv2.x,gv2.y,gv2.z,gv2.w, gv3.x,gv3.y,gv3.z,gv3.w};
            const float gi = gil[i];
            const int iblk = (i0 + i) >> 4;
            short o[16];
#pragma unroll
            for (int e = 0; e < 16; e++) {
                int j = j0 + jj + e;
                float a = avf[e];
                bool same = iblk == (j >> 4);
                bool pass;
                if (s == 0)      pass = (a > 0.7f) && same;
                else if (s == 1) pass = (a > 0.5f) && !same;
                else             pass = (a > 0.3f);
                float g = 1.0f / (1.0f + __expf(-(gi + gvf[e] + bg)));
                o[e] = f2bf(pass ? a * g : 0.0f);
            }
            *(int4*)&A_s[i][jj]     = ((int4*)o)[0];
            *(int4*)&A_s[i][jj + 8] = ((int4*)o)[1];
        }
        // stage B: FnT bf16 128 c x 128 k
        {
            const int c = t >> 1, k0l = (t & 1) << 6;
            const short* src = fnb + ((size_t)c << 10) + j0 + k0l;
#pragma unroll
            for (int e = 0; e < 8; e++)
                *(int4*)&B_s[c][k0l + e * 8] = *(const int4*)(src + e * 8);
        }
        __syncthreads();
        // MFMA: 2 M-subtiles x 2 N-subtiles (wave's 32 cols) x 4 K-steps
#pragma unroll
        for (int ks = 0; ks < 4; ks++) {
            const int ko = ks * 32 + quad * 8;
            s8v a0 = *(const s8v*)&A_s[l15][ko];
            s8v a1 = *(const s8v*)&A_s[16 + l15][ko];
            s8v b0 = *(const s8v*)&B_s[wid * 32 + l15][ko];
            s8v b1 = *(const s8v*)&B_s[wid * 32 + 16 + l15][ko];
            acc00 = __builtin_amdgcn_mfma_f32_16x16x32_bf16(a0, b0, acc00, 0, 0, 0);
            acc01 = __builtin_amdgcn_mfma_f32_16x16x32_bf16(a0, b1, acc01, 0, 0, 0);
            acc10 = __builtin_amdgcn_mfma_f32_16x16x32_bf16(a1, b0, acc10, 0, 0, 0);
            acc11 = __builtin_amdgcn_mfma_f32_16x16x32_bf16(a1, b1, acc11, 0, 0, 0);
        }
    }
    // epilogue: C layout col=lane&15, row=quad*4+reg
    {
        float* outp = ws + OOUT + ((size_t)sb * Nn) * 128;
        const int c0 = wid * 32 + l15;
        const int n0 = i0 + quad * 4;
#pragma unroll
        for (int r = 0; r < 4; r++) {
            atomicAdd(outp + (size_t)(n0 + r) * 128 + c0,           acc00[r]);
            atomicAdd(outp + (size_t)(n0 + r) * 128 + c0 + 16,      acc01[r]);
            atomicAdd(outp + (size_t)(n0 + 16 + r) * 128 + c0,      acc10[r]);
            atomicAdd(outp + (size_t)(n0 + 16 + r) * 128 + c0 + 16, acc11[r]);
        }
    }
}

// ---------------- add Fr -> OOUT, BN statistics ----------------
__global__ __launch_bounds__(256) void k_bnstat(float* __restrict__ ws) {
    const int tile = blockIdx.x, b = blockIdx.y, s = blockIdx.z;
    const int sb = s * 2 + b;
    const int t = threadIdx.x;
    __shared__ float bnr[4][128];
    const int c = t & 127, ih = t >> 7;
    const size_t base = ((size_t)sb * Nn + tile * 16) * 128;
    const float* Fr = ws + OFR + base;
    float* outp = ws + OOUT + base;
    float s1 = 0.0f, s2 = 0.0f;
#pragma unroll
    for (int q = 0; q < 8; q++) {
        int idx = (ih * 8 + q) * 128 + c;
        float v = outp[idx] + Fr[idx];
        outp[idx] = v;
        s1 += v;
        s2 = fmaf(v, v, s2);
    }
    bnr[ih][c] = s1;
    bnr[2 + ih][c] = s2;
    __syncthreads();
    if (t < 128) {
        atomicAdd(&ws[OBNS + s * 128 + t], bnr[0][t] + bnr[1][t]);
        atomicAdd(&ws[OBNQ + s * 128 + t], bnr[2][t] + bnr[3][t]);
    }
}

// ---------------- BN + residual + NodeAtt + relu + max-pool ----------------
__global__ __launch_bounds__(256) void k_bn_att(const float* __restrict__ bn_gamma,
                                                const float* __restrict__ bn_beta,
                                                const float* __restrict__ att_W,
                                                const float* __restrict__ att_b,
                                                float* __restrict__ ws) {
    const int tile = blockIdx.x, b = blockIdx.y, s = blockIdx.z;
    const int t = threadIdx.x;
    __shared__ float hl[16][132];
    const int sb = s * 2 + b;
    const int cthr = t & 127, ih = t >> 7;
    float mu = ws[OBNS + s * 128 + cthr] * (1.0f / 2048.0f);
    float ms = ws[OBNQ + s * 128 + cthr] * (1.0f / 2048.0f);
    float var = ms - mu * mu;
    float gam = bn_gamma[s * 128 + cthr];
    float bet = bn_beta[s * 128 + cthr];
    float scal = gam * rsqrtf(var + 1e-5f);
    const float* outp = ws + OOUT + ((size_t)sb * Nn + tile * 16) * 128;
    const float* F = ws + OF + ((size_t)b * Nn + tile * 16) * 128;
#pragma unroll
    for (int q = 0; q < 8; q++) {
        int il = ih * 8 + q;
        float v = outp[(size_t)il * 128 + cthr];
        hl[il][cthr] = scal * (v - mu) + bet + F[(size_t)il * 128 + cthr];
    }
    __syncthreads();
    float acc[8] = {0,0,0,0,0,0,0,0};
    const float* AW = att_W + s * 16384;
    for (int cin = 0; cin < 128; cin++) {
        float w = AW[cin * 128 + cthr];
#pragma unroll
        for (int q = 0; q < 8; q++) acc[q] = fmaf(hl[ih * 8 + q][cin], w, acc[q]);
    }
    float ab = att_b[s * 128 + cthr];
    float* ys = ws + OYS + ((size_t)sb * Nn + tile * 16) * 128;
    float mx = 0.0f;
#pragma unroll
    for (int q = 0; q < 8; q++) {
        int il = ih * 8 + q;
        float h = hl[il][cthr];
        float sg = 1.0f / (1.0f + __expf(-(acc[q] + ab)));
        float y = fmaxf(sg * h, 0.0f);
        ys[(size_t)il * 128 + cthr] = y;
        mx = fmaxf(mx, y);
    }
    atomicMax((unsigned int*)(ws + OPOOL + sb * 128 + cthr), __float_as_uint(mx));
}

// ---------------- pooled MLP ----------------
__global__ __launch_bounds__(128) void k_mlp(const float* __restrict__ W1, const float* __restrict__ b1,
                                             const float* __restrict__ W2, const float* __restrict__ b2,
                                             float* __restrict__ ws) {
    const int sb = blockIdx.x;      // s*2+b
    const int s = sb >> 1;
    const int t = threadIdx.x;      // cout
    __shared__ float pl[128], z1[128];
    pl[t] = ws[OPOOL + sb * 128 + t];
    __syncthreads();
    float a = b1[s * 128 + t];
    for (int cin = 0; cin < 128; cin++)
        a = fmaf(pl[cin], W1[s * 16384 + cin * 128 + t], a);
    z1[t] = fmaxf(a, 0.0f);
    __syncthreads();
    float a2 = b2[s * 128 + t];
    for (int cin = 0; cin < 128; cin++)
        a2 = fmaf(z1[cin], W2[s * 16384 + cin * 128 + t], a2);
    ws[OP2 + sb * 128 + t] = 1.0f / (1.0f + __expf(-a2));
}

// ---------------- scale attention coefficients ----------------
__global__ __launch_bounds__(256) void k_coef(const float* __restrict__ lineA_w,
                                              const float* __restrict__ lineA_b,
                                              float* __restrict__ ws) {
    __shared__ float av[2][3];
    const int t = threadIdx.x;
    if (t < 6) {
        int s = t >> 1, b = t & 1;
        float acc = lineA_b[s];
        for (int c = 0; c < 128; c++)
            acc = fmaf(ws[OP2 + (s * 2 + b) * 128 + c], lineA_w[s * 128 + c], acc);
        av[b][s] = acc;
    }
    __syncthreads();
    for (int e = t; e < 768; e += 256) {
        int s = e >> 8, b = (e >> 7) & 1;
        float m = fmaxf(av[b][0], fmaxf(av[b][1], av[b][2]));
        float e0 = __expf(av[b][0] - m), e1 = __expf(av[b][1] - m), e2 = __expf(av[b][2] - m);
        float A = (s == 0 ? e0 : (s == 1 ? e1 : e2)) / (e0 + e1 + e2);
        ws[OCOEF + e] = A * ws[OP2 + e];
    }
}

// ---------------- fused combination + lineFu matmul ----------------
__global__ __launch_bounds__(256) void k_fuse(const float* __restrict__ lineFu_W,
                                              const float* __restrict__ lineFu_b,
                                              float* __restrict__ ws) {
    const int tile = blockIdx.x, b = blockIdx.y;
    const int t = threadIdx.x;
    __shared__ float fl[16][132];
    const int cthr = t & 127, ih = t >> 7;
    float c0 = ws[OCOEF + (0 * 2 + b) * 128 + cthr];
    float c1 = ws[OCOEF + (1 * 2 + b) * 128 + cthr];
    float c2 = ws[OCOEF + (2 * 2 + b) * 128 + cthr];
#pragma unroll
    for (int q = 0; q < 8; q++) {
        int il = ih * 8 + q;
        size_t row = (size_t)(tile * 16 + il) * 128 + cthr;
        float v = c0 * ws[OYS + (size_t)(0 * 2 + b) * Nn * 128 + row]
                + c1 * ws[OYS + (size_t)(1 * 2 + b) * Nn * 128 + row]
                + c2 * ws[OYS + (size_t)(2 * 2 + b) * Nn * 128 + row];
        fl[il][cthr] = v;
    }
    __syncthreads();
    float acc[8] = {0,0,0,0,0,0,0,0};
    for (int cin = 0; cin < 128; cin++) {
        float w = lineFu_W[cin * 128 + cthr];
#pragma unroll
        for (int q = 0; q < 8; q++) acc[q] = fmaf(fl[ih * 8 + q][cin], w, acc[q]);
    }
    float bb = lineFu_b[cthr];
#pragma unroll
    for (int q = 0; q < 8; q++) {
        int row = tile * 16 + ih * 8 + q;
        ws[OYF + ((size_t)b * Nn + row) * 128 + cthr] = acc[q] + bb;
    }
}

// ---------------- reprojection + residual ----------------
__global__ __launch_bounds__(256) void k_reproj(const float* __restrict__ x,
                                                const float* __restrict__ ws,
                                                float* __restrict__ out) {
    const int blk = blockIdx.x, b = blockIdx.y;
    const int t = threadIdx.x;                 // pixel p
    __shared__ float yl[16][132];
    const float* YF = ws + OYF + ((size_t)b * Nn + blk * 16) * 128;
    for (int e = t; e < 16 * 128; e += 256) yl[e >> 7][e & 127] = YF[e];
    float qv[16];
    const float* Qg = ws + OQ + (size_t)(b * 64 + blk) * 16 * 256;
#pragma unroll
    for (int k = 0; k < 16; k++) qv[k] = Qg[k * 256 + t];
    __syncthreads();
    const int h = (blk >> 3) * 16 + (t >> 4);
    const int w = (blk & 7) * 16 + (t & 15);
    const float* xp = x + (size_t)b * Cc * HWp + (size_t)h * 128 + w;
    float* op = out + (size_t)b * Cc * HWp + (size_t)h * 128 + w;
    for (int c = 0; c < 128; c++) {
        float r = 0.0f;
#pragma unroll
        for (int k = 0; k < 16; k++) r = fmaf(qv[k], yl[k][c], r);
        op[(size_t)c * HWp] = r + xp[(size_t)c * HWp];
    }
}

extern "C" void kernel_launch(void* const* d_in, const int* in_sizes, int n_in,
                              void* d_out, int out_size, void* d_ws, size_t ws_size,
                              hipStream_t stream) {
    const float* x         = (const float*)d_in[0];
    const float* anchor    = (const float*)d_in[1];
    const float* sigma_raw = (const float*)d_in[2];
    const float* W_root    = (const float*)d_in[3];
    const float* W_nbr     = (const float*)d_in[4];
    const float* wgs       = (const float*)d_in[5];
    const float* wgd       = (const float*)d_in[6];
    const float* b_gate    = (const float*)d_in[7];
    const float* bn_gamma  = (const float*)d_in[8];
    const float* bn_beta   = (const float*)d_in[9];
    const float* att_W     = (const float*)d_in[10];
    const float* att_b     = (const float*)d_in[11];
    const float* mlp_W1    = (const float*)d_in[12];
    const float* mlp_b1    = (const float*)d_in[13];
    const float* mlp_W2    = (const float*)d_in[14];
    const float* mlp_b2    = (const float*)d_in[15];
    const float* lineA_w   = (const float*)d_in[16];
    const float* lineA_b   = (const float*)d_in[17];
    const float* lineFu_W  = (const float*)d_in[18];
    const float* lineFu_b  = (const float*)d_in[19];
    float* out = (float*)d_out;
    float* ws = (float*)d_ws;

    k_proj1  <<<dim3(64, 2, 4), dim3(256), 0, stream>>>(x, anchor, sigma_raw, ws);
    k_proj2  <<<dim3(64, 2),    dim3(256), 0, stream>>>(x, anchor, sigma_raw, ws);
    k_feat_mm<<<dim3(64, 2, 3), dim3(256), 0, stream>>>(W_root, W_nbr, wgs, wgd, ws);
    k_adj    <<<dim3(16, 16, 2),dim3(256), 0, stream>>>(ws);
    k_agg    <<<dim3(32, 2, 6), dim3(256), 0, stream>>>(b_gate, ws);
    k_bnstat <<<dim3(64, 2, 3), dim3(256), 0, stream>>>(ws);
    k_bn_att <<<dim3(64, 2, 3), dim3(256), 0, stream>>>(bn_gamma, bn_beta, att_W, att_b, ws);
    k_mlp    <<<dim3(6),        dim3(128), 0, stream>>>(mlp_W1, mlp_b1, mlp_W2, mlp_b2, ws);
    k_coef   <<<dim3(1),        dim3(256), 0, stream>>>(lineA_w, lineA_b, ws);
    k_fuse   <<<dim3(64, 2),    dim3(256), 0, stream>>>(lineFu_W, lineFu_b, ws);
    k_reproj <<<dim3(64, 2),    dim3(256), 0, stream>>>(x, ws, out);
}

// Round 8
// 227.602 us; speedup vs baseline: 1.2529x; 1.0723x over previous
//
#include <hip/hip_runtime.h>
#include <hip/hip_bf16.h>

// ---- problem constants ----
#define Bb    2
#define Cc    128
#define HWp   16384    // 128*128 (one channel plane)
#define NBLK  64
#define BNOD  16
#define NPix  256
#define Nn    1024

// ---- ws layout (float element offsets) ----
#define OQ    0u        // Q      [B][NBLK][BNOD][NP]   524288
#define OF    524288u   // feats  [B][N][C]             262144
#define OADJ  786432u   // adj    [B][N][N]            2097152
#define OFR   2883584u  // Fr     [S][B][N][C]          786432
#define OFN   3670016u  // FnT    bf16 [S*B][C][N]      (786432 bf16 = 393216 f-slots)
#define OGI   4456448u  // gi     [S][B][N]               6144
#define OGJ   4462592u  // gj     [S][B][N]               6144
#define OOUT  4468736u  // agg-acc / out [S][B][N][C]   786432
#define OBNS  5255168u  // bn sum [S][C]                   384
#define OBNQ  5255552u  // bn sq  [S][C]                   384
#define OPOOL 5255936u  // pool   [S][B][C]                768
#define OP2   5256704u  // pool2  [S][B][C]                768
#define OYS   5258240u  // ys     [S][B][N][C]          786432
// OFT (featsT f32 [B][C][N]) overlays OYS: live only proj2->fm_adj (OYS written later by k_bn_att).
#define OFT   OYS

typedef short s8v  __attribute__((ext_vector_type(8)));
typedef float f4v  __attribute__((ext_vector_type(4)));

__device__ __forceinline__ short f2bf(float f) {
    __hip_bfloat16 h = __float2bfloat16(f);
    return *reinterpret_cast<short*>(&h);
}

// ---------------- P1: logits + softmax over 16 nodes -> Q (pixel-split 4x, + zero-init) ----------------
__global__ __launch_bounds__(256) void k_proj1(const float* __restrict__ x,
                                               const float* __restrict__ anchor,
                                               const float* __restrict__ sigma_raw,
                                               float* __restrict__ ws) {
    const int blk = blockIdx.x, b = blockIdx.y, pg = blockIdx.z;
    const int t = threadIdx.x;
    if (blk == 0 && b == 0 && pg == 0) {
        for (int i = t; i < 1536; i += 256) ws[OBNS + i] = 0.0f;  // BNS+BNQ+POOL
    }
    __shared__ float2 pairs[128][16];          // 16 KB
    __shared__ float accp[4][64][17];          // 17.4 KB
    for (int e = t; e < 16 * 128; e += 256) {
        int k = e >> 7, c = e & 127;
        int n = blk * 16 + k;
        float a    = anchor[n * 128 + c];
        float sr   = sigma_raw[n * 128 + c];
        float isig = 1.0f + __expf(-sr);       // 1/sigmoid(sr)
        pairs[c][k] = make_float2(isig, a * isig);
    }
    __syncthreads();
    const int pl = t & 63, cq = t >> 6;
    const int p = pg * 64 + pl;
    const int h = (blk >> 3) * 16 + (p >> 4);
    const int w = (blk & 7) * 16 + (p & 15);
    const float* xp = x + (size_t)b * Cc * HWp + (size_t)h * 128 + w;
    float acc[16];
#pragma unroll
    for (int k = 0; k < 16; k++) acc[k] = 0.0f;
    for (int c = cq * 32; c < cq * 32 + 32; c++) {
        float pv = xp[(size_t)c * HWp];
#pragma unroll
        for (int k = 0; k < 16; k++) {
            float2 pr = pairs[c][k];
            float d = fmaf(pv, pr.x, -pr.y);
            acc[k] = fmaf(d, d, acc[k]);
        }
    }
#pragma unroll
    for (int k = 0; k < 16; k++) accp[cq][pl][k] = acc[k];
    __syncthreads();
    if (t < 64) {
        float a2[16];
#pragma unroll
        for (int k = 0; k < 16; k++)
            a2[k] = accp[0][t][k] + accp[1][t][k] + accp[2][t][k] + accp[3][t][k];
        float m = a2[0];
#pragma unroll
        for (int k = 1; k < 16; k++) m = fminf(m, a2[k]);
        float ssum = 0.0f, ev[16];
#pragma unroll
        for (int k = 0; k < 16; k++) { ev[k] = __expf(0.5f * (m - a2[k])); ssum += ev[k]; }
        float inv = 1.0f / ssum;
        float* Qp = ws + OQ + ((size_t)(b * 64 + blk) * 16) * 256 + p;
#pragma unroll
        for (int k = 0; k < 16; k++) Qp[k * 256] = ev[k] * inv;
    }
}

// ---------------- P2: nodes -> per-node L2 normalized feats (b128 LDS throughout) ----------------
__global__ __launch_bounds__(256) void k_proj2(const float* __restrict__ x,
                                               const float* __restrict__ anchor,
                                               const float* __restrict__ sigma_raw,
                                               float* __restrict__ ws) {
    const int blk = blockIdx.x, b = blockIdx.y;
    const int t = threadIdx.x;
    __shared__ __align__(16) float Ql[16][256];    // 16 KB
    __shared__ __align__(16) float pixl[32][260];  // 33.3 KB (stride 260: b128-aligned, 4-way max)
    __shared__ float vbuf[16][132];                // 8.4 KB
    __shared__ float invn[16];
    __shared__ float S0s[16];
    const float* Qg = ws + OQ + (size_t)(b * 64 + blk) * 16 * 256;
    for (int e = t; e < 1024; e += 256)
        *(float4*)&Ql[e >> 6][(e & 63) * 4] = *(const float4*)(Qg + (size_t)e * 4);
    __syncthreads();
    if (t < 16) {
        float s0 = 0.0f;
        for (int pc = 0; pc < 64; pc++) {
            float4 q = *(const float4*)&Ql[t][pc * 4];
            s0 += (q.x + q.y) + (q.z + q.w);
        }
        S0s[t] = s0;
    }
    __syncthreads();
    const int cq = t & 31;
    const int k0 = (t >> 5) * 2;
    const int n0 = blk * 16 + k0;
    const int h0 = (blk >> 3) * 16, w0 = (blk & 7) * 16;
    const float S0a = S0s[k0], S0b = S0s[k0 + 1];
    const float i0a = 1.0f / (S0a + 1e-9f);
    const float i0b = 1.0f / (S0b + 1e-9f);
    float nsqa = 0.0f, nsqb = 0.0f;
    for (int q = 0; q < 4; q++) {
        const int c = q * 32 + cq;
        __syncthreads();
        for (int e = t; e < 2048; e += 256) {
            int cc = e >> 6, f4 = e & 63;
            int pr = f4 >> 2, wq = (f4 & 3) * 4;
            *(float4*)&pixl[cc][f4 * 4] =
                *(const float4*)(x + ((size_t)b * Cc + q * 32 + cc) * HWp
                                 + (size_t)(h0 + pr) * 128 + w0 + wq);
        }
        __syncthreads();
        float s1a = 0.0f, s1b = 0.0f;
        for (int pc = 0; pc < 64; pc++) {
            float4 pv = *(const float4*)&pixl[cq][pc * 4];
            float4 qa = *(const float4*)&Ql[k0][pc * 4];
            float4 qb = *(const float4*)&Ql[k0 + 1][pc * 4];
            s1a = fmaf(pv.x, qa.x, fmaf(pv.y, qa.y, fmaf(pv.z, qa.z, fmaf(pv.w, qa.w, s1a))));
            s1b = fmaf(pv.x, qb.x, fmaf(pv.y, qb.y, fmaf(pv.z, qb.z, fmaf(pv.w, qb.w, s1b))));
        }
        float isa = 1.0f + __expf(-sigma_raw[(n0)     * 128 + c]);
        float isb = 1.0f + __expf(-sigma_raw[(n0 + 1) * 128 + c]);
        float aa  = anchor[(n0)     * 128 + c];
        float ab  = anchor[(n0 + 1) * 128 + c];
        float va = isa * (s1a - aa * S0a) * i0a;
        float vb = isb * (s1b - ab * S0b) * i0b;
        vbuf[k0][c]     = va;
        vbuf[k0 + 1][c] = vb;
        nsqa = fmaf(va, va, nsqa);
        nsqb = fmaf(vb, vb, nsqb);
    }
#pragma unroll
    for (int off = 16; off >= 1; off >>= 1) {
        nsqa += __shfl_xor(nsqa, off, 64);
        nsqb += __shfl_xor(nsqb, off, 64);
    }
    if (cq == 0) {
        invn[k0]     = 1.0f / fmaxf(sqrtf(nsqa), 1e-12f);
        invn[k0 + 1] = 1.0f / fmaxf(sqrtf(nsqb), 1e-12f);
    }
    __syncthreads();
    for (int e = t; e < 16 * 128; e += 256) {
        int k = e >> 7, c = e & 127;
        ws[OF + ((size_t)b * Nn + blk * 16 + k) * 128 + c] = vbuf[k][c] * invn[k];
    }
#pragma unroll
    for (int pass = 0; pass < 8; pass++) {
        int k = t & 15, c = (t >> 4) + pass * 16;
        ws[OFT + ((size_t)b * 128 + c) * 1024 + blk * 16 + k] = vbuf[k][c] * invn[k];
    }
}

// ---------------- merged: feats@W_root/W_nbr + gates (384 blocks)  ||  adj GEMM (512 blocks) ----------------
__global__ __launch_bounds__(256) void k_fm_adj(const float* __restrict__ W_root,
                                                const float* __restrict__ W_nbr,
                                                const float* __restrict__ wgs,
                                                const float* __restrict__ wgd,
                                                float* __restrict__ ws) {
    __shared__ __align__(16) float sm[8704];   // 34.8 KB shared by both branches
    const int bid = blockIdx.x;
    const int t = threadIdx.x;
    if (bid < 384) {
        // ---- feat_mm branch ----
        const int tile = bid & 63, b = (bid >> 6) & 1, s = bid >> 7;
        float (*fl)[132] = (float(*)[132])sm;
        const float* F = ws + OF + ((size_t)b * Nn + tile * 16) * 128;
        for (int e = t; e < 16 * 128; e += 256) fl[e >> 7][e & 127] = F[e];
        __syncthreads();
        const int cout = t & 127, ih = t >> 7;
        float ar[8], an[8];
#pragma unroll
        for (int q = 0; q < 8; q++) { ar[q] = 0.0f; an[q] = 0.0f; }
        const float* Wr = W_root + s * 16384;
        const float* Wn = W_nbr + s * 16384;
        for (int cin = 0; cin < 128; cin++) {
            float wr = Wr[cin * 128 + cout];
            float wn = Wn[cin * 128 + cout];
#pragma unroll
            for (int q = 0; q < 8; q++) {
                float f = fl[ih * 8 + q][cin];
                ar[q] = fmaf(f, wr, ar[q]);
                an[q] = fmaf(f, wn, an[q]);
            }
        }
        const int sb = s * 2 + b;
#pragma unroll
        for (int q = 0; q < 8; q++) {
            int row = tile * 16 + ih * 8 + q;
            ws[OFR + ((size_t)sb * Nn + row) * 128 + cout] = ar[q];
        }
        {
            short hb[8];
#pragma unroll
            for (int q = 0; q < 8; q++) hb[q] = f2bf(an[q]);
            short* fnb = (short*)(ws + OFN);
            *(int4*)(fnb + (((size_t)sb * 128 + cout) << 10) + tile * 16 + ih * 8) = *(int4*)hb;
        }
        if (t < 16) {
            int row = tile * 16 + t;
            float g1 = 0.0f, g2 = 0.0f;
            for (int c = 0; c < 128; c++) {
                float f = fl[t][c];
                g1 = fmaf(f, wgs[s * 128 + c], g1);
                g2 = fmaf(f, wgd[s * 128 + c], g2);
            }
            ws[OGI + (size_t)sb * Nn + row] = g1;
            ws[OGJ + (size_t)sb * Nn + row] = g2;
        }
    } else {
        // ---- adj branch ----
        const int e = bid - 384;
        const int jt = e & 15, it = (e >> 4) & 15, b = e >> 8;
        // zero the agg accumulator region (512 blocks x 1536 floats = 786432)
        for (int i = t; i < 1536; i += 256) ws[OOUT + (size_t)e * 1536 + i] = 0.0f;
        float (*FiT)[68] = (float(*)[68])sm;
        float (*FjT)[68] = (float(*)[68])(sm + 4352);
        const float* FT = ws + OFT + (size_t)b * 128 * 1024;
        const int tx = t & 15, ty = t >> 4;
        float acc[4][4];
#pragma unroll
        for (int r = 0; r < 4; r++)
#pragma unroll
            for (int ee = 0; ee < 4; ee++) acc[r][ee] = 0.0f;
        for (int ch = 0; ch < 2; ch++) {
            __syncthreads();
#pragma unroll
            for (int k = 0; k < 4; k++) {
                int idx = k * 256 + t;
                int cc = idx >> 4, n4 = (idx & 15) * 4;
                *(float4*)&FiT[cc][n4] =
                    *(const float4*)(FT + (size_t)(ch * 64 + cc) * 1024 + it * 64 + n4);
                *(float4*)&FjT[cc][n4] =
                    *(const float4*)(FT + (size_t)(ch * 64 + cc) * 1024 + jt * 64 + n4);
            }
            __syncthreads();
            for (int c = 0; c < 64; c++) {
                float4 fi = *(const float4*)&FiT[c][ty * 4];
                float4 fj = *(const float4*)&FjT[c][tx * 4];
                const float fiv[4] = {fi.x, fi.y, fi.z, fi.w};
                const float fjv[4] = {fj.x, fj.y, fj.z, fj.w};
#pragma unroll
                for (int r = 0; r < 4; r++)
#pragma unroll
                    for (int ee = 0; ee < 4; ee++)
                        acc[r][ee] = fmaf(fiv[r], fjv[ee], acc[r][ee]);
            }
        }
        float* A = ws + OADJ + (size_t)b * Nn * Nn;
#pragma unroll
        for (int r = 0; r < 4; r++) {
            *(float4*)&A[(size_t)(it * 64 + ty * 4 + r) * Nn + jt * 64 + tx * 4] =
                make_float4(acc[r][0], acc[r][1], acc[r][2], acc[r][3]);
        }
    }
}

// ---------------- MFMA aggregation: agg[sb] = W(adj,gate,mask)[1024x1024] @ Fn[1024x128] ----------------
__global__ __launch_bounds__(256) void k_agg(const float* __restrict__ b_gate,
                                             float* __restrict__ ws) {
    const int mt = blockIdx.x, kh = blockIdx.y, sb = blockIdx.z;
    const int s = sb >> 1, b = sb & 1;
    const int t = threadIdx.x;
    const int i0 = mt * 32, j00 = kh * 512;
    __shared__ short A_s[32][136];   // 8.7 KB
    __shared__ short B_s[128][136];  // 34.8 KB
    __shared__ float gil[32];
    if (t < 32) gil[t] = ws[OGI + (size_t)sb * Nn + i0 + t];
    const float bg = b_gate[s];
    const float* adj = ws + OADJ + (size_t)b * Nn * Nn;
    const float* gjp = ws + OGJ + (size_t)sb * Nn;
    const short* fnb = (const short*)(ws + OFN) + ((size_t)sb * 128 << 10);
    const int wid = t >> 6, lane = t & 63, quad = lane >> 4, l15 = lane & 15;
    f4v acc00 = {0,0,0,0}, acc01 = {0,0,0,0}, acc10 = {0,0,0,0}, acc11 = {0,0,0,0};

    for (int chunk = 0; chunk < 4; chunk++) {
        const int j0 = j00 + chunk * 128;
        __syncthreads();
        {
            const int i = t >> 3, jj = (t & 7) << 4;
            const float* ap = adj + (size_t)(i0 + i) * Nn + j0 + jj;
            float4 av0 = *(const float4*)(ap);
            float4 av1 = *(const float4*)(ap + 4);
            float4 av2 = *(const float4*)(ap + 8);
            float4 av3 = *(const float4*)(ap + 12);
            float4 gv0 = *(const float4*)(gjp + j0 + jj);
            float4 gv1 = *(const float4*)(gjp + j0 + jj + 4);
            float4 gv2 = *(const float4*)(gjp + j0 + jj + 8);
            float4 gv3 = *(const float4*)(gjp + j0 + jj + 12);
            float avf[16] = {av0.x,av0.y,av0.z,av0.w, av1.x,av1.y,av1.z,av1.w,
                             av2.x,av2.y,av2.z,av2.w, av3.x,av3.y,av3.z,av3.w};
            float gvf[16] = {gv0.x,gv0.y,gv0.z,gv0.w, gv1.x,gv1.y,gv1.z,gv1.w,
                             gv2.x,gv2.y,gv2.z,gv2.w, gv3.x,gv3.y,gv3.z,gv3.w};
            const float gi = gil[i];
            const int iblk = (i0 + i) >> 4;
            short o[16];
#pragma unroll
            for (int e = 0; e < 16; e++) {
                int j = j0 + jj + e;
                float a = avf[e];
                bool same = iblk == (j >> 4);
                bool pass;
                if (s == 0)      pass = (a > 0.7f) && same;
                else if (s == 1) pass = (a > 0.5f) && !same;
                else             pass = (a > 0.3f);
                float g = 1.0f / (1.0f + __expf(-(gi + gvf[e] + bg)));
                o[e] = f2bf(pass ? a * g : 0.0f);
            }
            *(int4*)&A_s[i][jj]     = ((int4*)o)[0];
            *(int4*)&A_s[i][jj + 8] = ((int4*)o)[1];
        }
        {
            const int c = t >> 1, k0l = (t & 1) << 6;
            const short* src = fnb + ((size_t)c << 10) + j0 + k0l;
#pragma unroll
            for (int e = 0; e < 8; e++)
                *(int4*)&B_s[c][k0l + e * 8] = *(const int4*)(src + e * 8);
        }
        __syncthreads();
#pragma unroll
        for (int ks = 0; ks < 4; ks++) {
            const int ko = ks * 32 + quad * 8;
            s8v a0 = *(const s8v*)&A_s[l15][ko];
            s8v a1 = *(const s8v*)&A_s[16 + l15][ko];
            s8v b0 = *(const s8v*)&B_s[wid * 32 + l15][ko];
            s8v b1 = *(const s8v*)&B_s[wid * 32 + 16 + l15][ko];
            acc00 = __builtin_amdgcn_mfma_f32_16x16x32_bf16(a0, b0, acc00, 0, 0, 0);
            acc01 = __builtin_amdgcn_mfma_f32_16x16x32_bf16(a0, b1, acc01, 0, 0, 0);
            acc10 = __builtin_amdgcn_mfma_f32_16x16x32_bf16(a1, b0, acc10, 0, 0, 0);
            acc11 = __builtin_amdgcn_mfma_f32_16x16x32_bf16(a1, b1, acc11, 0, 0, 0);
        }
    }
    {
        float* outp = ws + OOUT + ((size_t)sb * Nn) * 128;
        const int c0 = wid * 32 + l15;
        const int n0 = i0 + quad * 4;
#pragma unroll
        for (int r = 0; r < 4; r++) {
            atomicAdd(outp + (size_t)(n0 + r) * 128 + c0,           acc00[r]);
            atomicAdd(outp + (size_t)(n0 + r) * 128 + c0 + 16,      acc01[r]);
            atomicAdd(outp + (size_t)(n0 + 16 + r) * 128 + c0,      acc10[r]);
            atomicAdd(outp + (size_t)(n0 + 16 + r) * 128 + c0 + 16, acc11[r]);
        }
    }
}

// ---------------- add Fr -> OOUT, BN statistics ----------------
__global__ __launch_bounds__(256) void k_bnstat(float* __restrict__ ws) {
    const int tile = blockIdx.x, b = blockIdx.y, s = blockIdx.z;
    const int sb = s * 2 + b;
    const int t = threadIdx.x;
    __shared__ float bnr[4][128];
    const int c = t & 127, ih = t >> 7;
    const size_t base = ((size_t)sb * Nn + tile * 16) * 128;
    const float* Fr = ws + OFR + base;
    float* outp = ws + OOUT + base;
    float s1 = 0.0f, s2 = 0.0f;
#pragma unroll
    for (int q = 0; q < 8; q++) {
        int idx = (ih * 8 + q) * 128 + c;
        float v = outp[idx] + Fr[idx];
        outp[idx] = v;
        s1 += v;
        s2 = fmaf(v, v, s2);
    }
    bnr[ih][c] = s1;
    bnr[2 + ih][c] = s2;
    __syncthreads();
    if (t < 128) {
        atomicAdd(&ws[OBNS + s * 128 + t], bnr[0][t] + bnr[1][t]);
        atomicAdd(&ws[OBNQ + s * 128 + t], bnr[2][t] + bnr[3][t]);
    }
}

// ---------------- BN + residual + NodeAtt + relu + max-pool ----------------
__global__ __launch_bounds__(256) void k_bn_att(const float* __restrict__ bn_gamma,
                                                const float* __restrict__ bn_beta,
                                                const float* __restrict__ att_W,
                                                const float* __restrict__ att_b,
                                                float* __restrict__ ws) {
    const int tile = blockIdx.x, b = blockIdx.y, s = blockIdx.z;
    const int t = threadIdx.x;
    __shared__ float hl[16][132];
    const int sb = s * 2 + b;
    const int cthr = t & 127, ih = t >> 7;
    float mu = ws[OBNS + s * 128 + cthr] * (1.0f / 2048.0f);
    float ms = ws[OBNQ + s * 128 + cthr] * (1.0f / 2048.0f);
    float var = ms - mu * mu;
    float gam = bn_gamma[s * 128 + cthr];
    float bet = bn_beta[s * 128 + cthr];
    float scal = gam * rsqrtf(var + 1e-5f);
    const float* outp = ws + OOUT + ((size_t)sb * Nn + tile * 16) * 128;
    const float* F = ws + OF + ((size_t)b * Nn + tile * 16) * 128;
#pragma unroll
    for (int q = 0; q < 8; q++) {
        int il = ih * 8 + q;
        float v = outp[(size_t)il * 128 + cthr];
        hl[il][cthr] = scal * (v - mu) + bet + F[(size_t)il * 128 + cthr];
    }
    __syncthreads();
    float acc[8] = {0,0,0,0,0,0,0,0};
    const float* AW = att_W + s * 16384;
    for (int cin = 0; cin < 128; cin++) {
        float w = AW[cin * 128 + cthr];
#pragma unroll
        for (int q = 0; q < 8; q++) acc[q] = fmaf(hl[ih * 8 + q][cin], w, acc[q]);
    }
    float ab = att_b[s * 128 + cthr];
    float* ys = ws + OYS + ((size_t)sb * Nn + tile * 16) * 128;
    float mx = 0.0f;
#pragma unroll
    for (int q = 0; q < 8; q++) {
        int il = ih * 8 + q;
        float h = hl[il][cthr];
        float sg = 1.0f / (1.0f + __expf(-(acc[q] + ab)));
        float y = fmaxf(sg * h, 0.0f);
        ys[(size_t)il * 128 + cthr] = y;
        mx = fmaxf(mx, y);
    }
    atomicMax((unsigned int*)(ws + OPOOL + sb * 128 + cthr), __float_as_uint(mx));
}

// ---------------- pooled MLP ----------------
__global__ __launch_bounds__(128) void k_mlp(const float* __restrict__ W1, const float* __restrict__ b1,
                                             const float* __restrict__ W2, const float* __restrict__ b2,
                                             float* __restrict__ ws) {
    const int sb = blockIdx.x;      // s*2+b
    const int s = sb >> 1;
    const int t = threadIdx.x;      // cout
    __shared__ float pl[128], z1[128];
    pl[t] = ws[OPOOL + sb * 128 + t];
    __syncthreads();
    float a = b1[s * 128 + t];
    for (int cin = 0; cin < 128; cin++)
        a = fmaf(pl[cin], W1[s * 16384 + cin * 128 + t], a);
    z1[t] = fmaxf(a, 0.0f);
    __syncthreads();
    float a2 = b2[s * 128 + t];
    for (int cin = 0; cin < 128; cin++)
        a2 = fmaf(z1[cin], W2[s * 16384 + cin * 128 + t], a2);
    ws[OP2 + sb * 128 + t] = 1.0f / (1.0f + __expf(-a2));
}

// ---------------- fused: scale-coef + combination + lineFu matmul + reprojection + residual ----------------
__global__ __launch_bounds__(256) void k_fuse_reproj(const float* __restrict__ lineA_w,
                                                     const float* __restrict__ lineA_b,
                                                     const float* __restrict__ lineFu_W,
                                                     const float* __restrict__ lineFu_b,
                                                     const float* __restrict__ x,
                                                     float* __restrict__ ws,
                                                     float* __restrict__ out) {
    const int tile = blockIdx.x, b = blockIdx.y;
    const int t = threadIdx.x;
    __shared__ float fl[16][132];
    __shared__ __align__(16) float ylT[128][20];  // transposed yfin [c][k]
    __shared__ float av[3];
    // inline coef: av[s] = P2[s*2+b] . lineA_w[s] + lineA_b[s]
    if (t < 3) {
        float acc = lineA_b[t];
        for (int c = 0; c < 128; c++)
            acc = fmaf(ws[OP2 + (t * 2 + b) * 128 + c], lineA_w[t * 128 + c], acc);
        av[t] = acc;
    }
    __syncthreads();
    const float m = fmaxf(av[0], fmaxf(av[1], av[2]));
    const float e0 = __expf(av[0] - m), e1 = __expf(av[1] - m), e2 = __expf(av[2] - m);
    const float sinv = 1.0f / (e0 + e1 + e2);
    const int cthr = t & 127, ih = t >> 7;
    const float c0 = e0 * sinv * ws[OP2 + (0 * 2 + b) * 128 + cthr];
    const float c1 = e1 * sinv * ws[OP2 + (1 * 2 + b) * 128 + cthr];
    const float c2 = e2 * sinv * ws[OP2 + (2 * 2 + b) * 128 + cthr];
#pragma unroll
    for (int q = 0; q < 8; q++) {
        int il = ih * 8 + q;
        size_t row = (size_t)(tile * 16 + il) * 128 + cthr;
        float v = c0 * ws[OYS + (size_t)(0 * 2 + b) * Nn * 128 + row]
                + c1 * ws[OYS + (size_t)(1 * 2 + b) * Nn * 128 + row]
                + c2 * ws[OYS + (size_t)(2 * 2 + b) * Nn * 128 + row];
        fl[il][cthr] = v;
    }
    __syncthreads();
    float acc[8] = {0,0,0,0,0,0,0,0};
    for (int cin = 0; cin < 128; cin++) {
        float w = lineFu_W[cin * 128 + cthr];
#pragma unroll
        for (int q = 0; q < 8; q++) acc[q] = fmaf(fl[ih * 8 + q][cin], w, acc[q]);
    }
    const float bb = lineFu_b[cthr];
#pragma unroll
    for (int q = 0; q < 8; q++) ylT[cthr][ih * 8 + q] = acc[q] + bb;
    // reprojection: thread = pixel
    float qv[16];
    const float* Qg = ws + OQ + (size_t)(b * 64 + tile) * 16 * 256;
#pragma unroll
    for (int k = 0; k < 16; k++) qv[k] = Qg[k * 256 + t];
    __syncthreads();
    const int h = (tile >> 3) * 16 + (t >> 4);
    const int w = (tile & 7) * 16 + (t & 15);
    const float* xp = x + (size_t)b * Cc * HWp + (size_t)h * 128 + w;
    float* op = out + (size_t)b * Cc * HWp + (size_t)h * 128 + w;
    for (int c = 0; c < 128; c++) {
        float4 y0 = *(const float4*)&ylT[c][0];
        float4 y1 = *(const float4*)&ylT[c][4];
        float4 y2 = *(const float4*)&ylT[c][8];
        float4 y3 = *(const float4*)&ylT[c][12];
        float r = 0.0f;
        r = fmaf(qv[0],  y0.x, r); r = fmaf(qv[1],  y0.y, r);
        r = fmaf(qv[2],  y0.z, r); r = fmaf(qv[3],  y0.w, r);
        r = fmaf(qv[4],  y1.x, r); r = fmaf(qv[5],  y1.y, r);
        r = fmaf(qv[6],  y1.z, r); r = fmaf(qv[7],  y1.w, r);
        r = fmaf(qv[8],  y2.x, r); r = fmaf(qv[9],  y2.y, r);
        r = fmaf(qv[10], y2.z, r); r = fmaf(qv[11], y2.w, r);
        r = fmaf(qv[12], y3.x, r); r = fmaf(qv[13], y3.y, r);
        r = fmaf(qv[14], y3.z, r); r = fmaf(qv[15], y3.w, r);
        op[(size_t)c * HWp] = r + xp[(size_t)c * HWp];
    }
}

extern "C" void kernel_launch(void* const* d_in, const int* in_sizes, int n_in,
                              void* d_out, int out_size, void* d_ws, size_t ws_size,
                              hipStream_t stream) {
    const float* x         = (const float*)d_in[0];
    const float* anchor    = (const float*)d_in[1];
    const float* sigma_raw = (const float*)d_in[2];
    const float* W_root    = (const float*)d_in[3];
    const float* W_nbr     = (const float*)d_in[4];
    const float* wgs       = (const float*)d_in[5];
    const float* wgd       = (const float*)d_in[6];
    const float* b_gate    = (const float*)d_in[7];
    const float* bn_gamma  = (const float*)d_in[8];
    const float* bn_beta   = (const float*)d_in[9];
    const float* att_W     = (const float*)d_in[10];
    const float* att_b     = (const float*)d_in[11];
    const float* mlp_W1    = (const float*)d_in[12];
    const float* mlp_b1    = (const float*)d_in[13];
    const float* mlp_W2    = (const float*)d_in[14];
    const float* mlp_b2    = (const float*)d_in[15];
    const float* lineA_w   = (const float*)d_in[16];
    const float* lineA_b   = (const float*)d_in[17];
    const float* lineFu_W  = (const float*)d_in[18];
    const float* lineFu_b  = (const float*)d_in[19];
    float* out = (float*)d_out;
    float* ws = (float*)d_ws;

    k_proj1      <<<dim3(64, 2, 4), dim3(256), 0, stream>>>(x, anchor, sigma_raw, ws);
    k_proj2      <<<dim3(64, 2),    dim3(256), 0, stream>>>(x, anchor, sigma_raw, ws);
    k_fm_adj     <<<dim3(896),      dim3(256), 0, stream>>>(W_root, W_nbr, wgs, wgd, ws);
    k_agg        <<<dim3(32, 2, 6), dim3(256), 0, stream>>>(b_gate, ws);
    k_bnstat     <<<dim3(64, 2, 3), dim3(256), 0, stream>>>(ws);
    k_bn_att     <<<dim3(64, 2, 3), dim3(256), 0, stream>>>(bn_gamma, bn_beta, att_W, att_b, ws);
    k_mlp        <<<dim3(6),        dim3(128), 0, stream>>>(mlp_W1, mlp_b1, mlp_W2, mlp_b2, ws);
    k_fuse_reproj<<<dim3(64, 2),    dim3(256), 0, stream>>>(lineA_w, lineA_b, lineFu_W, lineFu_b, x, ws, out);
}

// Round 9
// 221.361 us; speedup vs baseline: 1.2882x; 1.0282x over previous
//
#include <hip/hip_runtime.h>
#include <hip/hip_bf16.h>

// ---- problem constants ----
#define Bb    2
#define Cc    128
#define HWp   16384    // 128*128 (one channel plane)
#define NBLK  64
#define BNOD  16
#define NPix  256
#define Nn    1024

// ---- ws layout (float element offsets) ----
#define OQ    0u        // Q      [B][NBLK][BNOD][NP]   524288
#define OF    524288u   // feats  [B][N][C]             262144
#define OFR   2883584u  // Fr     [S][B][N][C]          786432
#define OFN   3670016u  // FnT    bf16 [S*B][C][N]      (786432 bf16 = 393216 f-slots)
#define OGI   4456448u  // gi     [S][B][N]               6144
#define OGJ   4462592u  // gj     [S][B][N]               6144
#define OOUT  4468736u  // agg-acc / out [S][B][N][C]   786432
#define OBNS  5255168u  // bn sum [S][C]                   384
#define OBNQ  5255552u  // bn sq  [S][C]                   384
#define OPOOL 5255936u  // pool   [S][B][C]                768
#define OP2   5256704u  // pool2  [S][B][C]                768
#define OYS   5258240u  // ys     [S][B][N][C]          786432
#define OAW   6306816u  // masked-gated W bf16 [6][1024][1024] (3145728 f-slots)
// OFT (featsT f32 [B][C][N]) overlays OYS: live only proj2->fm_adj (OYS written later by k_bn_att).
#define OFT   OYS

typedef short s8v  __attribute__((ext_vector_type(8)));
typedef float f4v  __attribute__((ext_vector_type(4)));

__device__ __forceinline__ short f2bf(float f) {
    __hip_bfloat16 h = __float2bfloat16(f);
    return *reinterpret_cast<short*>(&h);
}

// ---------------- P1: logits + softmax over 16 nodes -> Q (pixel-split 4x, + zero-init) ----------------
__global__ __launch_bounds__(256) void k_proj1(const float* __restrict__ x,
                                               const float* __restrict__ anchor,
                                               const float* __restrict__ sigma_raw,
                                               float* __restrict__ ws) {
    const int blk = blockIdx.x, b = blockIdx.y, pg = blockIdx.z;
    const int t = threadIdx.x;
    if (blk == 0 && b == 0 && pg == 0) {
        for (int i = t; i < 1536; i += 256) ws[OBNS + i] = 0.0f;  // BNS+BNQ+POOL
    }
    __shared__ float2 pairs[128][16];          // 16 KB
    __shared__ float accp[4][64][17];          // 17.4 KB
    for (int e = t; e < 16 * 128; e += 256) {
        int k = e >> 7, c = e & 127;
        int n = blk * 16 + k;
        float a    = anchor[n * 128 + c];
        float sr   = sigma_raw[n * 128 + c];
        float isig = 1.0f + __expf(-sr);       // 1/sigmoid(sr)
        pairs[c][k] = make_float2(isig, a * isig);
    }
    __syncthreads();
    const int pl = t & 63, cq = t >> 6;
    const int p = pg * 64 + pl;
    const int h = (blk >> 3) * 16 + (p >> 4);
    const int w = (blk & 7) * 16 + (p & 15);
    const float* xp = x + (size_t)b * Cc * HWp + (size_t)h * 128 + w;
    float acc[16];
#pragma unroll
    for (int k = 0; k < 16; k++) acc[k] = 0.0f;
    for (int c = cq * 32; c < cq * 32 + 32; c++) {
        float pv = xp[(size_t)c * HWp];
#pragma unroll
        for (int k = 0; k < 16; k++) {
            float2 pr = pairs[c][k];
            float d = fmaf(pv, pr.x, -pr.y);
            acc[k] = fmaf(d, d, acc[k]);
        }
    }
#pragma unroll
    for (int k = 0; k < 16; k++) accp[cq][pl][k] = acc[k];
    __syncthreads();
    if (t < 64) {
        float a2[16];
#pragma unroll
        for (int k = 0; k < 16; k++)
            a2[k] = accp[0][t][k] + accp[1][t][k] + accp[2][t][k] + accp[3][t][k];
        float m = a2[0];
#pragma unroll
        for (int k = 1; k < 16; k++) m = fminf(m, a2[k]);
        float ssum = 0.0f, ev[16];
#pragma unroll
        for (int k = 0; k < 16; k++) { ev[k] = __expf(0.5f * (m - a2[k])); ssum += ev[k]; }
        float inv = 1.0f / ssum;
        float* Qp = ws + OQ + ((size_t)(b * 64 + blk) * 16) * 256 + p;
#pragma unroll
        for (int k = 0; k < 16; k++) Qp[k * 256] = ev[k] * inv;
    }
}

// ---------------- P2: nodes -> per-node L2 normalized feats (b128 LDS throughout) ----------------
__global__ __launch_bounds__(256) void k_proj2(const float* __restrict__ x,
                                               const float* __restrict__ anchor,
                                               const float* __restrict__ sigma_raw,
                                               float* __restrict__ ws) {
    const int blk = blockIdx.x, b = blockIdx.y;
    const int t = threadIdx.x;
    __shared__ __align__(16) float Ql[16][256];    // 16 KB
    __shared__ __align__(16) float pixl[32][260];  // 33.3 KB
    __shared__ float vbuf[16][132];                // 8.4 KB
    __shared__ float invn[16];
    __shared__ float S0s[16];
    const float* Qg = ws + OQ + (size_t)(b * 64 + blk) * 16 * 256;
    for (int e = t; e < 1024; e += 256)
        *(float4*)&Ql[e >> 6][(e & 63) * 4] = *(const float4*)(Qg + (size_t)e * 4);
    __syncthreads();
    if (t < 16) {
        float s0 = 0.0f;
        for (int pc = 0; pc < 64; pc++) {
            float4 q = *(const float4*)&Ql[t][pc * 4];
            s0 += (q.x + q.y) + (q.z + q.w);
        }
        S0s[t] = s0;
    }
    __syncthreads();
    const int cq = t & 31;
    const int k0 = (t >> 5) * 2;
    const int n0 = blk * 16 + k0;
    const int h0 = (blk >> 3) * 16, w0 = (blk & 7) * 16;
    const float S0a = S0s[k0], S0b = S0s[k0 + 1];
    const float i0a = 1.0f / (S0a + 1e-9f);
    const float i0b = 1.0f / (S0b + 1e-9f);
    float nsqa = 0.0f, nsqb = 0.0f;
    for (int q = 0; q < 4; q++) {
        const int c = q * 32 + cq;
        __syncthreads();
        for (int e = t; e < 2048; e += 256) {
            int cc = e >> 6, f4 = e & 63;
            int pr = f4 >> 2, wq = (f4 & 3) * 4;
            *(float4*)&pixl[cc][f4 * 4] =
                *(const float4*)(x + ((size_t)b * Cc + q * 32 + cc) * HWp
                                 + (size_t)(h0 + pr) * 128 + w0 + wq);
        }
        __syncthreads();
        float s1a = 0.0f, s1b = 0.0f;
        for (int pc = 0; pc < 64; pc++) {
            float4 pv = *(const float4*)&pixl[cq][pc * 4];
            float4 qa = *(const float4*)&Ql[k0][pc * 4];
            float4 qb = *(const float4*)&Ql[k0 + 1][pc * 4];
            s1a = fmaf(pv.x, qa.x, fmaf(pv.y, qa.y, fmaf(pv.z, qa.z, fmaf(pv.w, qa.w, s1a))));
            s1b = fmaf(pv.x, qb.x, fmaf(pv.y, qb.y, fmaf(pv.z, qb.z, fmaf(pv.w, qb.w, s1b))));
        }
        float isa = 1.0f + __expf(-sigma_raw[(n0)     * 128 + c]);
        float isb = 1.0f + __expf(-sigma_raw[(n0 + 1) * 128 + c]);
        float aa  = anchor[(n0)     * 128 + c];
        float ab  = anchor[(n0 + 1) * 128 + c];
        float va = isa * (s1a - aa * S0a) * i0a;
        float vb = isb * (s1b - ab * S0b) * i0b;
        vbuf[k0][c]     = va;
        vbuf[k0 + 1][c] = vb;
        nsqa = fmaf(va, va, nsqa);
        nsqb = fmaf(vb, vb, nsqb);
    }
#pragma unroll
    for (int off = 16; off >= 1; off >>= 1) {
        nsqa += __shfl_xor(nsqa, off, 64);
        nsqb += __shfl_xor(nsqb, off, 64);
    }
    if (cq == 0) {
        invn[k0]     = 1.0f / fmaxf(sqrtf(nsqa), 1e-12f);
        invn[k0 + 1] = 1.0f / fmaxf(sqrtf(nsqb), 1e-12f);
    }
    __syncthreads();
    for (int e = t; e < 16 * 128; e += 256) {
        int k = e >> 7, c = e & 127;
        ws[OF + ((size_t)b * Nn + blk * 16 + k) * 128 + c] = vbuf[k][c] * invn[k];
    }
#pragma unroll
    for (int pass = 0; pass < 8; pass++) {
        int k = t & 15, c = (t >> 4) + pass * 16;
        ws[OFT + ((size_t)b * 128 + c) * 1024 + blk * 16 + k] = vbuf[k][c] * invn[k];
    }
}

// ---------------- merged: feats@W (384 blocks) || adj GEMM + mask/gate -> bf16 W matrices (512 blocks) ----------------
__global__ __launch_bounds__(256) void k_fm_adj(const float* __restrict__ W_root,
                                                const float* __restrict__ W_nbr,
                                                const float* __restrict__ wgs,
                                                const float* __restrict__ wgd,
                                                const float* __restrict__ b_gate,
                                                float* __restrict__ ws) {
    __shared__ __align__(16) float sm[8704];   // 34.8 KB shared by both branches
    const int bid = blockIdx.x;
    const int t = threadIdx.x;
    if (bid < 384) {
        // ---- feat_mm branch ----
        const int tile = bid & 63, b = (bid >> 6) & 1, s = bid >> 7;
        float (*fl)[132] = (float(*)[132])sm;
        const float* F = ws + OF + ((size_t)b * Nn + tile * 16) * 128;
        for (int e = t; e < 16 * 128; e += 256) fl[e >> 7][e & 127] = F[e];
        __syncthreads();
        const int cout = t & 127, ih = t >> 7;
        float ar[8], an[8];
#pragma unroll
        for (int q = 0; q < 8; q++) { ar[q] = 0.0f; an[q] = 0.0f; }
        const float* Wr = W_root + s * 16384;
        const float* Wn = W_nbr + s * 16384;
        for (int cin = 0; cin < 128; cin++) {
            float wr = Wr[cin * 128 + cout];
            float wn = Wn[cin * 128 + cout];
#pragma unroll
            for (int q = 0; q < 8; q++) {
                float f = fl[ih * 8 + q][cin];
                ar[q] = fmaf(f, wr, ar[q]);
                an[q] = fmaf(f, wn, an[q]);
            }
        }
        const int sb = s * 2 + b;
#pragma unroll
        for (int q = 0; q < 8; q++) {
            int row = tile * 16 + ih * 8 + q;
            ws[OFR + ((size_t)sb * Nn + row) * 128 + cout] = ar[q];
        }
        {
            short hb[8];
#pragma unroll
            for (int q = 0; q < 8; q++) hb[q] = f2bf(an[q]);
            short* fnb = (short*)(ws + OFN);
            *(int4*)(fnb + (((size_t)sb * 128 + cout) << 10) + tile * 16 + ih * 8) = *(int4*)hb;
        }
        if (t < 16) {
            int row = tile * 16 + t;
            float g1 = 0.0f, g2 = 0.0f;
            for (int c = 0; c < 128; c++) {
                float f = fl[t][c];
                g1 = fmaf(f, wgs[s * 128 + c], g1);
                g2 = fmaf(f, wgd[s * 128 + c], g2);
            }
            ws[OGI + (size_t)sb * Nn + row] = g1;
            ws[OGJ + (size_t)sb * Nn + row] = g2;
        }
    } else {
        // ---- adj branch: 64x64 cosine tile in registers -> mask+gate -> bf16 W ----
        const int e = bid - 384;
        const int jt = e & 15, it = (e >> 4) & 15, b = e >> 8;
        __shared__ float gis[3][64], gjs[3][64], bgs[3];
        if (t < 192) {
            int s = t >> 6, ii = t & 63;
            gis[s][ii] = ws[OGI + (size_t)(s * 2 + b) * Nn + it * 64 + ii];
            gjs[s][ii] = ws[OGJ + (size_t)(s * 2 + b) * Nn + jt * 64 + ii];
        }
        if (t < 3) bgs[t] = b_gate[t];
        // zero the agg accumulator region (512 blocks x 1536 floats = 786432)
        for (int i = t; i < 1536; i += 256) ws[OOUT + (size_t)e * 1536 + i] = 0.0f;
        float (*FiT)[68] = (float(*)[68])sm;
        float (*FjT)[68] = (float(*)[68])(sm + 4352);
        const float* FT = ws + OFT + (size_t)b * 128 * 1024;
        const int tx = t & 15, ty = t >> 4;
        float acc[4][4];
#pragma unroll
        for (int r = 0; r < 4; r++)
#pragma unroll
            for (int ee = 0; ee < 4; ee++) acc[r][ee] = 0.0f;
        for (int ch = 0; ch < 2; ch++) {
            __syncthreads();
#pragma unroll
            for (int k = 0; k < 4; k++) {
                int idx = k * 256 + t;
                int cc = idx >> 4, n4 = (idx & 15) * 4;
                *(float4*)&FiT[cc][n4] =
                    *(const float4*)(FT + (size_t)(ch * 64 + cc) * 1024 + it * 64 + n4);
                *(float4*)&FjT[cc][n4] =
                    *(const float4*)(FT + (size_t)(ch * 64 + cc) * 1024 + jt * 64 + n4);
            }
            __syncthreads();
            for (int c = 0; c < 64; c++) {
                float4 fi = *(const float4*)&FiT[c][ty * 4];
                float4 fj = *(const float4*)&FjT[c][tx * 4];
                const float fiv[4] = {fi.x, fi.y, fi.z, fi.w};
                const float fjv[4] = {fj.x, fj.y, fj.z, fj.w};
#pragma unroll
                for (int r = 0; r < 4; r++)
#pragma unroll
                    for (int ee = 0; ee < 4; ee++)
                        acc[r][ee] = fmaf(fiv[r], fjv[ee], acc[r][ee]);
            }
        }
        short* AW = (short*)(ws + OAW);
#pragma unroll
        for (int s = 0; s < 3; s++) {
            const int sb = s * 2 + b;
#pragma unroll
            for (int r = 0; r < 4; r++) {
                const int i = it * 64 + ty * 4 + r;
                const int iblk = i >> 4;
                const float giv = gis[s][ty * 4 + r];
                short o[4];
#pragma unroll
                for (int ee = 0; ee < 4; ee++) {
                    const int j = jt * 64 + tx * 4 + ee;
                    float a = acc[r][ee];
                    bool same = iblk == (j >> 4);
                    bool pass;
                    if (s == 0)      pass = (a > 0.7f) && same;
                    else if (s == 1) pass = (a > 0.5f) && !same;
                    else             pass = (a > 0.3f);
                    float g = 1.0f / (1.0f + __expf(-(giv + gjs[s][tx * 4 + ee] + bgs[s])));
                    o[ee] = f2bf(pass ? a * g : 0.0f);
                }
                *(int2*)(AW + (((size_t)sb << 20) + ((size_t)i << 10) + jt * 64 + tx * 4)) = *(int2*)o;
            }
        }
    }
}

// ---------------- MFMA aggregation: agg[sb] = AW[sb][1024x1024] @ Fn[1024x128] ----------------
// grid (32 M-tiles, 2 K-halves, 6 sb); 256 threads (4 waves).
__global__ __launch_bounds__(256) void k_agg(float* __restrict__ ws) {
    const int mt = blockIdx.x, kh = blockIdx.y, sb = blockIdx.z;
    const int t = threadIdx.x;
    const int i0 = mt * 32, j00 = kh * 512;
    __shared__ short A_s[32][136];   // 8.7 KB
    __shared__ short B_s[128][136];  // 34.8 KB
    const short* AWp = (const short*)(ws + OAW) + ((size_t)sb << 20);
    const short* fnb = (const short*)(ws + OFN) + ((size_t)sb * 128 << 10);
    const int wid = t >> 6, lane = t & 63, quad = lane >> 4, l15 = lane & 15;
    f4v acc00 = {0,0,0,0}, acc01 = {0,0,0,0}, acc10 = {0,0,0,0}, acc11 = {0,0,0,0};

    for (int chunk = 0; chunk < 4; chunk++) {
        const int j0 = j00 + chunk * 128;
        __syncthreads();
        // stage A: 32 i x 128 k bf16 (pure copy)
        {
            const int i = t >> 3, kk = (t & 7) << 4;
            const short* src = AWp + ((size_t)(i0 + i) << 10) + j0 + kk;
            *(int4*)&A_s[i][kk]     = *(const int4*)(src);
            *(int4*)&A_s[i][kk + 8] = *(const int4*)(src + 8);
        }
        // stage B: FnT bf16 128 c x 128 k
        {
            const int c = t >> 1, k0l = (t & 1) << 6;
            const short* src = fnb + ((size_t)c << 10) + j0 + k0l;
#pragma unroll
            for (int e = 0; e < 8; e++)
                *(int4*)&B_s[c][k0l + e * 8] = *(const int4*)(src + e * 8);
        }
        __syncthreads();
#pragma unroll
        for (int ks = 0; ks < 4; ks++) {
            const int ko = ks * 32 + quad * 8;
            s8v a0 = *(const s8v*)&A_s[l15][ko];
            s8v a1 = *(const s8v*)&A_s[16 + l15][ko];
            s8v b0 = *(const s8v*)&B_s[wid * 32 + l15][ko];
            s8v b1 = *(const s8v*)&B_s[wid * 32 + 16 + l15][ko];
            acc00 = __builtin_amdgcn_mfma_f32_16x16x32_bf16(a0, b0, acc00, 0, 0, 0);
            acc01 = __builtin_amdgcn_mfma_f32_16x16x32_bf16(a0, b1, acc01, 0, 0, 0);
            acc10 = __builtin_amdgcn_mfma_f32_16x16x32_bf16(a1, b0, acc10, 0, 0, 0);
            acc11 = __builtin_amdgcn_mfma_f32_16x16x32_bf16(a1, b1, acc11, 0, 0, 0);
        }
    }
    {
        float* outp = ws + OOUT + ((size_t)sb * Nn) * 128;
        const int c0 = wid * 32 + l15;
        const int n0 = i0 + quad * 4;
#pragma unroll
        for (int r = 0; r < 4; r++) {
            atomicAdd(outp + (size_t)(n0 + r) * 128 + c0,           acc00[r]);
            atomicAdd(outp + (size_t)(n0 + r) * 128 + c0 + 16,      acc01[r]);
            atomicAdd(outp + (size_t)(n0 + 16 + r) * 128 + c0,      acc10[r]);
            atomicAdd(outp + (size_t)(n0 + 16 + r) * 128 + c0 + 16, acc11[r]);
        }
    }
}

// ---------------- add Fr -> OOUT, BN statistics ----------------
__global__ __launch_bounds__(256) void k_bnstat(float* __restrict__ ws) {
    const int tile = blockIdx.x, b = blockIdx.y, s = blockIdx.z;
    const int sb = s * 2 + b;
    const int t = threadIdx.x;
    __shared__ float bnr[4][128];
    const int c = t & 127, ih = t >> 7;
    const size_t base = ((size_t)sb * Nn + tile * 16) * 128;
    const float* Fr = ws + OFR + base;
    float* outp = ws + OOUT + base;
    float s1 = 0.0f, s2 = 0.0f;
#pragma unroll
    for (int q = 0; q < 8; q++) {
        int idx = (ih * 8 + q) * 128 + c;
        float v = outp[idx] + Fr[idx];
        outp[idx] = v;
        s1 += v;
        s2 = fmaf(v, v, s2);
    }
    bnr[ih][c] = s1;
    bnr[2 + ih][c] = s2;
    __syncthreads();
    if (t < 128) {
        atomicAdd(&ws[OBNS + s * 128 + t], bnr[0][t] + bnr[1][t]);
        atomicAdd(&ws[OBNQ + s * 128 + t], bnr[2][t] + bnr[3][t]);
    }
}

// ---------------- BN + residual + NodeAtt + relu + max-pool ----------------
__global__ __launch_bounds__(256) void k_bn_att(const float* __restrict__ bn_gamma,
                                                const float* __restrict__ bn_beta,
                                                const float* __restrict__ att_W,
                                                const float* __restrict__ att_b,
                                                float* __restrict__ ws) {
    const int tile = blockIdx.x, b = blockIdx.y, s = blockIdx.z;
    const int t = threadIdx.x;
    __shared__ float hl[16][132];
    const int sb = s * 2 + b;
    const int cthr = t & 127, ih = t >> 7;
    float mu = ws[OBNS + s * 128 + cthr] * (1.0f / 2048.0f);
    float ms = ws[OBNQ + s * 128 + cthr] * (1.0f / 2048.0f);
    float var = ms - mu * mu;
    float gam = bn_gamma[s * 128 + cthr];
    float bet = bn_beta[s * 128 + cthr];
    float scal = gam * rsqrtf(var + 1e-5f);
    const float* outp = ws + OOUT + ((size_t)sb * Nn + tile * 16) * 128;
    const float* F = ws + OF + ((size_t)b * Nn + tile * 16) * 128;
#pragma unroll
    for (int q = 0; q < 8; q++) {
        int il = ih * 8 + q;
        float v = outp[(size_t)il * 128 + cthr];
        hl[il][cthr] = scal * (v - mu) + bet + F[(size_t)il * 128 + cthr];
    }
    __syncthreads();
    float acc[8] = {0,0,0,0,0,0,0,0};
    const float* AW = att_W + s * 16384;
    for (int cin = 0; cin < 128; cin++) {
        float w = AW[cin * 128 + cthr];
#pragma unroll
        for (int q = 0; q < 8; q++) acc[q] = fmaf(hl[ih * 8 + q][cin], w, acc[q]);
    }
    float ab = att_b[s * 128 + cthr];
    float* ys = ws + OYS + ((size_t)sb * Nn + tile * 16) * 128;
    float mx = 0.0f;
#pragma unroll
    for (int q = 0; q < 8; q++) {
        int il = ih * 8 + q;
        float h = hl[il][cthr];
        float sg = 1.0f / (1.0f + __expf(-(acc[q] + ab)));
        float y = fmaxf(sg * h, 0.0f);
        ys[(size_t)il * 128 + cthr] = y;
        mx = fmaxf(mx, y);
    }
    atomicMax((unsigned int*)(ws + OPOOL + sb * 128 + cthr), __float_as_uint(mx));
}

// ---------------- pooled MLP ----------------
__global__ __launch_bounds__(128) void k_mlp(const float* __restrict__ W1, const float* __restrict__ b1,
                                             const float* __restrict__ W2, const float* __restrict__ b2,
                                             float* __restrict__ ws) {
    const int sb = blockIdx.x;      // s*2+b
    const int s = sb >> 1;
    const int t = threadIdx.x;      // cout
    __shared__ float pl[128], z1[128];
    pl[t] = ws[OPOOL + sb * 128 + t];
    __syncthreads();
    float a = b1[s * 128 + t];
    for (int cin = 0; cin < 128; cin++)
        a = fmaf(pl[cin], W1[s * 16384 + cin * 128 + t], a);
    z1[t] = fmaxf(a, 0.0f);
    __syncthreads();
    float a2 = b2[s * 128 + t];
    for (int cin = 0; cin < 128; cin++)
        a2 = fmaf(z1[cin], W2[s * 16384 + cin * 128 + t], a2);
    ws[OP2 + sb * 128 + t] = 1.0f / (1.0f + __expf(-a2));
}

// ---------------- fused: coef + combination + lineFu + reprojection + residual (2-way cout split) ----------------
__global__ __launch_bounds__(256) void k_fuse_reproj(const float* __restrict__ lineA_w,
                                                     const float* __restrict__ lineA_b,
                                                     const float* __restrict__ lineFu_W,
                                                     const float* __restrict__ lineFu_b,
                                                     const float* __restrict__ x,
                                                     float* __restrict__ ws,
                                                     float* __restrict__ out) {
    const int tile = blockIdx.x, b = blockIdx.y, chh = blockIdx.z;
    const int t = threadIdx.x;
    __shared__ float fl[16][132];
    __shared__ __align__(16) float ylT[64][20];
    __shared__ float av[3];
    if (t < 3) {
        float acc = lineA_b[t];
        for (int c = 0; c < 128; c++)
            acc = fmaf(ws[OP2 + (t * 2 + b) * 128 + c], lineA_w[t * 128 + c], acc);
        av[t] = acc;
    }
    __syncthreads();
    const float m = fmaxf(av[0], fmaxf(av[1], av[2]));
    const float e0 = __expf(av[0] - m), e1 = __expf(av[1] - m), e2 = __expf(av[2] - m);
    const float sinv = 1.0f / (e0 + e1 + e2);
    const int cthr = t & 127, ih = t >> 7;
    const float c0 = e0 * sinv * ws[OP2 + (0 * 2 + b) * 128 + cthr];
    const float c1 = e1 * sinv * ws[OP2 + (1 * 2 + b) * 128 + cthr];
    const float c2 = e2 * sinv * ws[OP2 + (2 * 2 + b) * 128 + cthr];
#pragma unroll
    for (int q = 0; q < 8; q++) {
        int il = ih * 8 + q;
        size_t row = (size_t)(tile * 16 + il) * 128 + cthr;
        float v = c0 * ws[OYS + (size_t)(0 * 2 + b) * Nn * 128 + row]
                + c1 * ws[OYS + (size_t)(1 * 2 + b) * Nn * 128 + row]
                + c2 * ws[OYS + (size_t)(2 * 2 + b) * Nn * 128 + row];
        fl[il][cthr] = v;
    }
    __syncthreads();
    // lineFu matmul: this block computes couts chh*64..+64; thread = (cout 64, row-group 4)
    {
        const int co = chh * 64 + (t & 63), rg = t >> 6;
        float acc[4] = {0, 0, 0, 0};
        for (int cin = 0; cin < 128; cin++) {
            float w = lineFu_W[cin * 128 + co];
#pragma unroll
            for (int q = 0; q < 4; q++) acc[q] = fmaf(fl[rg * 4 + q][cin], w, acc[q]);
        }
        const float bb = lineFu_b[co];
#pragma unroll
        for (int q = 0; q < 4; q++) ylT[t & 63][rg * 4 + q] = acc[q] + bb;
    }
    // reprojection: thread = pixel, 64 channels of this half
    float qv[16];
    const float* Qg = ws + OQ + (size_t)(b * 64 + tile) * 16 * 256;
#pragma unroll
    for (int k = 0; k < 16; k++) qv[k] = Qg[k * 256 + t];
    __syncthreads();
    const int h = (tile >> 3) * 16 + (t >> 4);
    const int w = (tile & 7) * 16 + (t & 15);
    const float* xp = x + (size_t)b * Cc * HWp + (size_t)h * 128 + w;
    float* op = out + (size_t)b * Cc * HWp + (size_t)h * 128 + w;
    for (int c = 0; c < 64; c++) {
        float4 y0 = *(const float4*)&ylT[c][0];
        float4 y1 = *(const float4*)&ylT[c][4];
        float4 y2 = *(const float4*)&ylT[c][8];
        float4 y3 = *(const float4*)&ylT[c][12];
        float r = 0.0f;
        r = fmaf(qv[0],  y0.x, r); r = fmaf(qv[1],  y0.y, r);
        r = fmaf(qv[2],  y0.z, r); r = fmaf(qv[3],  y0.w, r);
        r = fmaf(qv[4],  y1.x, r); r = fmaf(qv[5],  y1.y, r);
        r = fmaf(qv[6],  y1.z, r); r = fmaf(qv[7],  y1.w, r);
        r = fmaf(qv[8],  y2.x, r); r = fmaf(qv[9],  y2.y, r);
        r = fmaf(qv[10], y2.z, r); r = fmaf(qv[11], y2.w, r);
        r = fmaf(qv[12], y3.x, r); r = fmaf(qv[13], y3.y, r);
        r = fmaf(qv[14], y3.z, r); r = fmaf(qv[15], y3.w, r);
        const size_t off = (size_t)(chh * 64 + c) * HWp;
        op[off] = r + xp[off];
    }
}

extern "C" void kernel_launch(void* const* d_in, const int* in_sizes, int n_in,
                              void* d_out, int out_size, void* d_ws, size_t ws_size,
                              hipStream_t stream) {
    const float* x         = (const float*)d_in[0];
    const float* anchor    = (const float*)d_in[1];
    const float* sigma_raw = (const float*)d_in[2];
    const float* W_root    = (const float*)d_in[3];
    const float* W_nbr     = (const float*)d_in[4];
    const float* wgs       = (const float*)d_in[5];
    const float* wgd       = (const float*)d_in[6];
    const float* b_gate    = (const float*)d_in[7];
    const float* bn_gamma  = (const float*)d_in[8];
    const float* bn_beta   = (const float*)d_in[9];
    const float* att_W     = (const float*)d_in[10];
    const float* att_b     = (const float*)d_in[11];
    const float* mlp_W1    = (const float*)d_in[12];
    const float* mlp_b1    = (const float*)d_in[13];
    const float* mlp_W2    = (const float*)d_in[14];
    const float* mlp_b2    = (const float*)d_in[15];
    const float* lineA_w   = (const float*)d_in[16];
    const float* lineA_b   = (const float*)d_in[17];
    const float* lineFu_W  = (const float*)d_in[18];
    const float* lineFu_b  = (const float*)d_in[19];
    float* out = (float*)d_out;
    float* ws = (float*)d_ws;

    k_proj1      <<<dim3(64, 2, 4), dim3(256), 0, stream>>>(x, anchor, sigma_raw, ws);
    k_proj2      <<<dim3(64, 2),    dim3(256), 0, stream>>>(x, anchor, sigma_raw, ws);
    k_fm_adj     <<<dim3(896),      dim3(256), 0, stream>>>(W_root, W_nbr, wgs, wgd, b_gate, ws);
    k_agg        <<<dim3(32, 2, 6), dim3(256), 0, stream>>>(ws);
    k_bnstat     <<<dim3(64, 2, 3), dim3(256), 0, stream>>>(ws);
    k_bn_att     <<<dim3(64, 2, 3), dim3(256), 0, stream>>>(bn_gamma, bn_beta, att_W, att_b, ws);
    k_mlp        <<<dim3(6),        dim3(128), 0, stream>>>(mlp_W1, mlp_b1, mlp_W2, mlp_b2, ws);
    k_fuse_reproj<<<dim3(64, 2, 2), dim3(256), 0, stream>>>(lineA_w, lineA_b, lineFu_W, lineFu_b, x, ws, out);
}